// Round 8
// baseline (444.201 us; speedup 1.0000x reference)
//
#include <hip/hip_runtime.h>

#define B_ 8
#define T_ 2048
#define E_ 256
#define H_ 8
#define DH_ 32
#define SCALING_ 0.17677669529663687f   // 1/sqrt(32)
#define LOG2E_ 1.4426950408889634f
// Q is pre-scaled by SCALING*log2(e): scores exit QK in log2 domain -> hw exp2
#define QSCALE_ (SCALING_ * LOG2E_)

typedef short bf16x8 __attribute__((ext_vector_type(8)));   // 8 bf16 in 4 VGPRs
typedef float floatx4 __attribute__((ext_vector_type(4)));

__device__ __forceinline__ unsigned short f2bf(float f) {
    union { float f; unsigned u; } v; v.f = f;
    unsigned r = v.u + 0x7FFFu + ((v.u >> 16) & 1u);   // RNE
    return (unsigned short)(r >> 16);
}

// pack 2 f32 -> 2 bf16 (round-half-up) in 3 VALU: add, add, v_perm_b32
__device__ __forceinline__ unsigned pk2(float a, float b) {
    union { float f; unsigned u; } ua, ub;
    ua.f = a; ub.f = b;
    return __builtin_amdgcn_perm(ub.u + 0x8000u, ua.u + 0x8000u, 0x07060302u);
}

__device__ __forceinline__ float fexp2(float x) {
#if __has_builtin(__builtin_amdgcn_exp2f)
    return __builtin_amdgcn_exp2f(x);
#else
    return exp2f(x);
#endif
}

__device__ __forceinline__ bf16x8 pack8(float4 a, float4 b) {
    bf16x8 o;
    o[0] = (short)f2bf(a.x); o[1] = (short)f2bf(a.y);
    o[2] = (short)f2bf(a.z); o[3] = (short)f2bf(a.w);
    o[4] = (short)f2bf(b.x); o[5] = (short)f2bf(b.y);
    o[6] = (short)f2bf(b.z); o[7] = (short)f2bf(b.w);
    return o;
}

// ---------------------------------------------------------------------------
// Kernel 0: weight prepack fp32 -> bf16 (tiny: 128 blocks).
// Also zeroes mask_nz (replaces the separate hipMemsetAsync dispatch).
// ---------------------------------------------------------------------------
__global__ __launch_bounds__(256) void prepack_kernel(
    const float* __restrict__ Wq, const float* __restrict__ Wk,
    const float* __restrict__ Wv, const float* __restrict__ Wo,
    unsigned short* __restrict__ Wpack, int* __restrict__ mask_nz) {
    if (blockIdx.x == 0 && threadIdx.x == 0) *mask_nz = 0;
    int idx = blockIdx.x * 256 + threadIdx.x;   // 32768 threads
    int m = idx >> 13;                           // matrix id 0..3
    int e = (idx & 8191) * 8;
    const float* W = (m == 0) ? Wq : (m == 1) ? Wk : (m == 2) ? Wv : Wo;
    float4 a = ((const float4*)(W + e))[0];
    float4 b = ((const float4*)(W + e))[1];
    *(bf16x8*)(Wpack + (size_t)m * 65536 + e) = pack8(a, b);
}

// ---------------------------------------------------------------------------
// Kernel 1: QKV projection (blocks 0..1535) FUSED with mask nonzero check
// (blocks 1536..3583) — the 128 MB mask scan overlaps the GEMM instead of
// serializing. mask_nz pre-zeroed by prepack_kernel; -0.0 -> slow path.
// ---------------------------------------------------------------------------
__global__ __launch_bounds__(256, 4) void qkvmask_kernel(
    const float* __restrict__ hs, const float* __restrict__ oq,
    const unsigned short* __restrict__ Wpack,
    const float* __restrict__ bq, const float* __restrict__ bk,
    const float* __restrict__ bv,
    unsigned short* __restrict__ Qw, unsigned short* __restrict__ Kw,
    unsigned short* __restrict__ Vtw,
    const int* __restrict__ mask, int* __restrict__ mask_nz) {
    if (blockIdx.x >= 1536) {
        // ---- mask scan: 2048 blocks, grid-stride int4 OR ----
        const size_t n4 = (size_t)B_ * T_ * T_ / 4;   // 8,388,608 int4
        size_t gid = (size_t)(blockIdx.x - 1536) * 256 + threadIdx.x;
        int acc = 0;
        for (size_t i = gid; i < n4; i += (size_t)2048 * 256) {
            int4 v = ((const int4*)mask)[i];
            acc |= v.x | v.y | v.z | v.w;
        }
        if (__builtin_amdgcn_ballot_w64(acc != 0)) {
            if ((threadIdx.x & 63) == 0) atomicOr(mask_nz, 1);
        }
        return;
    }
    __shared__ __align__(16) unsigned short sX[32][264];
    const int mat = blockIdx.x >> 9;          // 0=Q, 1=K, 2=V
    const int mbase = (blockIdx.x & 511) * 32;
    const int b = mbase >> 11, tbase = mbase & 2047;
    const int tid = threadIdx.x;

#pragma unroll
    for (int i = 0; i < 8; ++i) {
        int idx = tid + i * 256;
        int row = idx >> 6, c4 = idx & 63;
        float4 hv = ((const float4*)(hs + (size_t)(mbase + row) * E_))[c4];
        if (mat < 2) {
            float4 ov = ((const float4*)(oq + (size_t)(mbase + row) * E_))[c4];
            hv.x += ov.x; hv.y += ov.y; hv.z += ov.z; hv.w += ov.w;
        }
        ushort4 pb;
        pb.x = f2bf(hv.x); pb.y = f2bf(hv.y); pb.z = f2bf(hv.z); pb.w = f2bf(hv.w);
        *(ushort4*)&sX[row][c4 * 4] = pb;
    }
    __syncthreads();

    const int wave = tid >> 6, lane = tid & 63;
    const int quad = lane >> 4, m16 = lane & 15;
    const unsigned short* W = Wpack + (size_t)mat * 65536;

    bf16x8 xf[2][8];
#pragma unroll
    for (int hgrp = 0; hgrp < 2; ++hgrp)
#pragma unroll
        for (int kc = 0; kc < 8; ++kc)
            xf[hgrp][kc] = *(const bf16x8*)&sX[hgrp * 16 + m16][kc * 32 + quad * 8];

    if (mat < 2) {
        const float* bias = (mat == 0) ? bq : bk;
        unsigned short* Out = (mat == 0) ? Qw : Kw;
#pragma unroll
        for (int i = 0; i < 4; ++i) {
            int nt = wave * 4 + i;
            int ecol = nt * 16 + m16;
            const unsigned short* wrow = W + (size_t)ecol * E_;
            floatx4 acc0 = {0.f, 0.f, 0.f, 0.f};
            floatx4 acc1 = {0.f, 0.f, 0.f, 0.f};
#pragma unroll
            for (int kc = 0; kc < 8; ++kc) {
                bf16x8 bf = *(const bf16x8*)(wrow + kc * 32 + quad * 8);
                acc0 = __builtin_amdgcn_mfma_f32_16x16x32_bf16(xf[0][kc], bf, acc0, 0, 0, 0);
                acc1 = __builtin_amdgcn_mfma_f32_16x16x32_bf16(xf[1][kc], bf, acc1, 0, 0, 0);
            }
            float bs = bias[ecol];
            int h = ecol >> 5, dh = ecol & 31;
            size_t base0 = (((size_t)b * H_ + h) * T_ + (tbase + quad * 4)) * DH_ + dh;
            size_t base1 = base0 + (size_t)16 * DH_;
#pragma unroll
            for (int r = 0; r < 4; ++r) {
                float v0 = acc0[r] + bs, v1 = acc1[r] + bs;
                if (mat == 0) { v0 *= QSCALE_; v1 *= QSCALE_; }
                Out[base0 + (size_t)r * DH_] = f2bf(v0);
                Out[base1 + (size_t)r * DH_] = f2bf(v1);
            }
        }
    } else {
#pragma unroll
        for (int i = 0; i < 4; ++i) {
            int et = wave * 4 + i;
            int erow = et * 16 + m16;
            const unsigned short* wrow = W + (size_t)erow * E_;
            floatx4 acc0 = {0.f, 0.f, 0.f, 0.f};
            floatx4 acc1 = {0.f, 0.f, 0.f, 0.f};
#pragma unroll
            for (int kc = 0; kc < 8; ++kc) {
                bf16x8 wf = *(const bf16x8*)(wrow + kc * 32 + quad * 8);
                acc0 = __builtin_amdgcn_mfma_f32_16x16x32_bf16(wf, xf[0][kc], acc0, 0, 0, 0);
                acc1 = __builtin_amdgcn_mfma_f32_16x16x32_bf16(wf, xf[1][kc], acc1, 0, 0, 0);
            }
            int t0 = tbase + m16, t1 = t0 + 16;
#pragma unroll
            for (int r = 0; r < 4; ++r) {
                int ev = et * 16 + quad * 4 + r;
                int h = ev >> 5, dh = ev & 31;
                size_t vb = (((size_t)b * H_ + h) * DH_ + dh) * T_;
                Vtw[vb + t0] = f2bf(acc0[r] + bv[ev]);
                Vtw[vb + t1] = f2bf(acc1[r] + bv[ev]);
            }
        }
    }
}

// ---------------------------------------------------------------------------
// Kernel 2: flash attention — R7 base (verified: 99.7 µs, VGPR 104, no spill)
// + R8: PV LAGS QK BY ONE 64-KEY PHASE (double-buffered 64-key sPT chunks).
//  Evidence: R7 confirmed the (256,2) VGPR-half=128 budget and V-in-reg
//  staging (+17%). Remaining chain: PV(p) depended on softmax(p)'s LDS
//  write within the same phase -> MFMA pipe idle during every exp2 burst.
//  Now phase p runs: QK(p) | K prefetch(p+2) | PV(p-1) (independent of
//  sc(p) -> overlaps exp2) | stage V(p) | exp2/pack/write buf[p&1].
//  LDS write->read gap = one full phase; V loads keep a phase of cover.
//  Rescale exactness: O rescaled to m(p) AFTER PV(p-1) (both at m(p-1)) —
//  identical semantics to the per-hf update R0-R7 used.
//  This is R5's schedule, which spilled at cap128 (VGPR half 64); at
//  (256,2) the half is 128 and R7 measured 104 used with vf twice this
//  size — fits. Tripwire: WRITE_SIZE ~8 MB, VGPR <= ~120.
// ---------------------------------------------------------------------------
__device__ __forceinline__ void softmax_write(
    floatx4 (&scA)[4], floatx4 (&scB)[4], int mnz,
    const float* MbA, const float* MbB, int S0,
    float& mprevA, float& mprevB,
    floatx4& O0A, floatx4& O1A, floatx4& LA,
    floatx4& O0B, floatx4& O1B, floatx4& LB,
    unsigned short (*bufA)[72], unsigned short (*bufB)[72],
    int m16, int quad, int swz) {
    if (!mnz) {
        // FAST PATH: raw exp2, pack, LDS. No stats, no adds.
#pragma unroll
        for (int c = 0; c < 4; ++c) {
            float a0 = fexp2(scA[c][0]), a1 = fexp2(scA[c][1]);
            float a2 = fexp2(scA[c][2]), a3 = fexp2(scA[c][3]);
            float b0 = fexp2(scB[c][0]), b1 = fexp2(scB[c][1]);
            float b2 = fexp2(scB[c][2]), b3 = fexp2(scB[c][3]);
            uint2 wa = {pk2(a0, a1), pk2(a2, a3)};
            uint2 wb = {pk2(b0, b1), pk2(b2, b3)};
            int col = ((c * 16) ^ swz) + quad * 4;
            *(uint2*)&bufA[m16][col] = wa;
            *(uint2*)&bufB[m16][col] = wb;
        }
    } else {
        // SLOW PATH: online softmax in log2 domain; mask scaled by log2e.
#pragma unroll
        for (int c = 0; c < 4; ++c) {
            float4 ma = *(const float4*)(MbA + S0 + c * 16);
            float4 mb = *(const float4*)(MbB + S0 + c * 16);
            scA[c][0] += ma.x * LOG2E_; scA[c][1] += ma.y * LOG2E_;
            scA[c][2] += ma.z * LOG2E_; scA[c][3] += ma.w * LOG2E_;
            scB[c][0] += mb.x * LOG2E_; scB[c][1] += mb.y * LOG2E_;
            scB[c][2] += mb.z * LOG2E_; scB[c][3] += mb.w * LOG2E_;
        }
        float mlA = -1e30f, mlB = -1e30f;
#pragma unroll
        for (int c = 0; c < 4; ++c) {
            mlA = fmaxf(fmaxf(fmaxf(scA[c][0], scA[c][1]), fmaxf(scA[c][2], scA[c][3])), mlA);
            mlB = fmaxf(fmaxf(fmaxf(scB[c][0], scB[c][1]), fmaxf(scB[c][2], scB[c][3])), mlB);
        }
        mlA = fmaxf(mlA, __shfl_xor(mlA, 16, 64));
        mlA = fmaxf(mlA, __shfl_xor(mlA, 32, 64));
        mlB = fmaxf(mlB, __shfl_xor(mlB, 16, 64));
        mlB = fmaxf(mlB, __shfl_xor(mlB, 32, 64));
        float mnA = fmaxf(mprevA, mlA), mnB = fmaxf(mprevB, mlB);
        float alA = fexp2(mprevA - mnA), alB = fexp2(mprevB - mnB);
        mprevA = mnA; mprevB = mnB;
#pragma unroll
        for (int r = 0; r < 4; ++r) {
            O0A[r] *= alA; O1A[r] *= alA; LA[r] *= alA;
            O0B[r] *= alB; O1B[r] *= alB; LB[r] *= alB;
        }
#pragma unroll
        for (int c = 0; c < 4; ++c) {
            float a0 = fexp2(scA[c][0] - mnA), a1 = fexp2(scA[c][1] - mnA);
            float a2 = fexp2(scA[c][2] - mnA), a3 = fexp2(scA[c][3] - mnA);
            float b0 = fexp2(scB[c][0] - mnB), b1 = fexp2(scB[c][1] - mnB);
            float b2 = fexp2(scB[c][2] - mnB), b3 = fexp2(scB[c][3] - mnB);
            uint2 wa = {pk2(a0, a1), pk2(a2, a3)};
            uint2 wb = {pk2(b0, b1), pk2(b2, b3)};
            int col = ((c * 16) ^ swz) + quad * 4;
            *(uint2*)&bufA[m16][col] = wa;
            *(uint2*)&bufB[m16][col] = wb;
        }
    }
}

__global__ __launch_bounds__(256, 2) void attn_kernel(
    const unsigned short* __restrict__ Qw, const unsigned short* __restrict__ Kw,
    const unsigned short* __restrict__ Vtw, const float* __restrict__ mask,
    const int* __restrict__ mask_nz, unsigned short* __restrict__ attnw) {
    // [wave][stream][buf][q][col] — two 64-key chunks per wave/stream.
    __shared__ __align__(16) unsigned short sPT[4][2][2][16][72];
    const int tid = threadIdx.x;
    const int wave = tid >> 6, lane = tid & 63;
    const int quad = lane >> 4, m16 = lane & 15;
    const int swz = (m16 & 8) * 4;            // 0 or 32 shorts (64 B granule)
    const int bh = blockIdx.x & 63, qt = blockIdx.x >> 6;   // bh%8==h -> XCD
    const int b = bh >> 3, h = bh & 7;
    const int qA = qt * 128 + wave * 32;
    const int qB = qA + 16;
    const int mnz = *mask_nz;

    bf16x8 qfragA = *(const bf16x8*)(Qw + ((size_t)bh * T_ + qA + m16) * DH_ + quad * 8);
    bf16x8 qfragB = *(const bf16x8*)(Qw + ((size_t)bh * T_ + qB + m16) * DH_ + quad * 8);
    const unsigned short* Kb = Kw + (size_t)bh * T_ * DH_;
    const unsigned short* Vb = Vtw + (size_t)bh * DH_ * T_;
    const float* MbA = mask + ((size_t)b * T_ + qA + m16) * T_ + quad * 4;
    const float* MbB = MbA + (size_t)16 * T_;

    floatx4 O0A = {0.f, 0.f, 0.f, 0.f}, O1A = {0.f, 0.f, 0.f, 0.f};
    floatx4 O0B = {0.f, 0.f, 0.f, 0.f}, O1B = {0.f, 0.f, 0.f, 0.f};
    floatx4 LA  = {0.f, 0.f, 0.f, 0.f}, LB  = {0.f, 0.f, 0.f, 0.f};  // l accumulators
    float mprevA = -1e30f, mprevB = -1e30f;
    const floatx4 zero = {0.f, 0.f, 0.f, 0.f};

    bf16x8 ones8;
#pragma unroll
    for (int i = 0; i < 8; ++i) ones8[i] = (short)0x3F80;   // bf16 1.0

    // kf[0..3] = even-phase keys, kf[4..7] = odd-phase keys.
    bf16x8 kf[8];
#pragma unroll
    for (int c = 0; c < 8; ++c)
        kf[c] = *(const bf16x8*)(Kb + (size_t)(c * 16 + m16) * DH_ + quad * 8);

    // V stage for phase 0 (keys 0..63): 2 sub-blocks x 2 V-row-groups.
    const unsigned short* vr0 = Vb + (size_t)m16 * T_;
    const unsigned short* vr1 = Vb + (size_t)(16 + m16) * T_;
    bf16x8 vf0[2], vf1[2];
#pragma unroll
    for (int sb = 0; sb < 2; ++sb) {
        vf0[sb] = *(const bf16x8*)(vr0 + sb * 32 + quad * 8);
        vf1[sb] = *(const bf16x8*)(vr1 + sb * 32 + quad * 8);
    }

    for (int p = 0; p < 32; ++p) {
        const int s0 = p * 64;
        const int h4 = (p & 1) * 4;
        floatx4 scA[4], scB[4];
        // QK for phase p
#pragma unroll
        for (int c = 0; c < 4; ++c) {
            scA[c] = __builtin_amdgcn_mfma_f32_16x16x32_bf16(kf[h4 + c], qfragA, zero, 0, 0, 0);
            scB[c] = __builtin_amdgcn_mfma_f32_16x16x32_bf16(kf[h4 + c], qfragB, zero, 0, 0, 0);
        }
        // K prefetch for phase p+2
        if (p < 30) {
#pragma unroll
            for (int c = 0; c < 4; ++c)
                kf[h4 + c] = *(const bf16x8*)(
                    Kb + (size_t)(s0 + 128 + c * 16 + m16) * DH_ + quad * 8);
        }
        // PV for phase p-1: LDS written a full phase ago, V staged a phase
        // ago; independent of sc(p) -> overlaps the exp2 burst below.
        if (p > 0) {
            const int pb = (p - 1) & 1;
#pragma unroll
            for (int sb = 0; sb < 2; ++sb) {
                int col = ((sb * 32) ^ swz) + quad * 8;
                bf16x8 pbA = *(const bf16x8*)&sPT[wave][0][pb][m16][col];
                bf16x8 pbB = *(const bf16x8*)&sPT[wave][1][pb][m16][col];
                O0A = __builtin_amdgcn_mfma_f32_16x16x32_bf16(vf0[sb], pbA, O0A, 0, 0, 0);
                O0B = __builtin_amdgcn_mfma_f32_16x16x32_bf16(vf0[sb], pbB, O0B, 0, 0, 0);
                O1A = __builtin_amdgcn_mfma_f32_16x16x32_bf16(vf1[sb], pbA, O1A, 0, 0, 0);
                O1B = __builtin_amdgcn_mfma_f32_16x16x32_bf16(vf1[sb], pbB, O1B, 0, 0, 0);
                LA  = __builtin_amdgcn_mfma_f32_16x16x32_bf16(ones8, pbA, LA, 0, 0, 0);
                LB  = __builtin_amdgcn_mfma_f32_16x16x32_bf16(ones8, pbB, LB, 0, 0, 0);
            }
            // V stage for phase p (consumed next iteration).
#pragma unroll
            for (int sb = 0; sb < 2; ++sb) {
                vf0[sb] = *(const bf16x8*)(vr0 + s0 + sb * 32 + quad * 8);
                vf1[sb] = *(const bf16x8*)(vr1 + s0 + sb * 32 + quad * 8);
            }
        }
        // softmax + pack + LDS write for phase p into buf[p&1]
        softmax_write(scA, scB, mnz, MbA, MbB, s0, mprevA, mprevB,
                      O0A, O1A, LA, O0B, O1B, LB,
                      sPT[wave][0][p & 1], sPT[wave][1][p & 1], m16, quad, swz);
    }

    // ---- drain: PV for phase 31 (buf 1, vf holds V(31)) ----
#pragma unroll
    for (int sb = 0; sb < 2; ++sb) {
        int col = ((sb * 32) ^ swz) + quad * 8;
        bf16x8 pbA = *(const bf16x8*)&sPT[wave][0][1][m16][col];
        bf16x8 pbB = *(const bf16x8*)&sPT[wave][1][1][m16][col];
        O0A = __builtin_amdgcn_mfma_f32_16x16x32_bf16(vf0[sb], pbA, O0A, 0, 0, 0);
        O0B = __builtin_amdgcn_mfma_f32_16x16x32_bf16(vf0[sb], pbB, O0B, 0, 0, 0);
        O1A = __builtin_amdgcn_mfma_f32_16x16x32_bf16(vf1[sb], pbA, O1A, 0, 0, 0);
        O1B = __builtin_amdgcn_mfma_f32_16x16x32_bf16(vf1[sb], pbB, O1B, 0, 0, 0);
        LA  = __builtin_amdgcn_mfma_f32_16x16x32_bf16(ones8, pbA, LA, 0, 0, 0);
        LB  = __builtin_amdgcn_mfma_f32_16x16x32_bf16(ones8, pbB, LB, 0, 0, 0);
    }

    // LA/LB rows all hold l[q=m16] — no shuffles needed.
    float invA = 1.0f / LA[0], invB = 1.0f / LB[0];
    size_t obA = ((size_t)b * T_ + qA + m16) * E_ + h * DH_ + quad * 4;
    size_t obB = ((size_t)b * T_ + qB + m16) * E_ + h * DH_ + quad * 4;
    ushort4 sv;
    sv.x = f2bf(O0A[0] * invA); sv.y = f2bf(O0A[1] * invA);
    sv.z = f2bf(O0A[2] * invA); sv.w = f2bf(O0A[3] * invA);
    *(ushort4*)(attnw + obA) = sv;
    sv.x = f2bf(O1A[0] * invA); sv.y = f2bf(O1A[1] * invA);
    sv.z = f2bf(O1A[2] * invA); sv.w = f2bf(O1A[3] * invA);
    *(ushort4*)(attnw + obA + 16) = sv;
    sv.x = f2bf(O0B[0] * invB); sv.y = f2bf(O0B[1] * invB);
    sv.z = f2bf(O0B[2] * invB); sv.w = f2bf(O0B[3] * invB);
    *(ushort4*)(attnw + obB) = sv;
    sv.x = f2bf(O1B[0] * invB); sv.y = f2bf(O1B[1] * invB);
    sv.z = f2bf(O1B[2] * invB); sv.w = f2bf(O1B[3] * invB);
    *(ushort4*)(attnw + obB + 16) = sv;
}

// ---------------------------------------------------------------------------
// Kernel 3: output projection: out = attn @ Wo^T + bo  (fp32 out, bf16 weights)
// ---------------------------------------------------------------------------
__global__ __launch_bounds__(256, 4) void oproj_kernel(
    const unsigned short* __restrict__ attnw, const unsigned short* __restrict__ Wob,
    const float* __restrict__ bo, float* __restrict__ out) {
    __shared__ __align__(16) unsigned short sA[16][264];
    const int tid = threadIdx.x;
    const int mbase = blockIdx.x * 16;
#pragma unroll
    for (int i = 0; i < 4; ++i) {
        int idx = tid + i * 256;
        int row = idx >> 6, c4 = idx & 63;
        const ushort4 a = ((const ushort4*)(attnw + (size_t)(mbase + row) * E_))[c4];
        *(ushort4*)&sA[row][c4 * 4] = a;
    }
    __syncthreads();
    const int wave = tid >> 6, lane = tid & 63;
    const int quad = lane >> 4, m16 = lane & 15;

    bf16x8 af[8];
#pragma unroll
    for (int kc = 0; kc < 8; ++kc)
        af[kc] = *(const bf16x8*)&sA[m16][kc * 32 + quad * 8];

#pragma unroll
    for (int i = 0; i < 4; ++i) {
        int nt = wave * 4 + i;
        int ecol = nt * 16 + m16;
        const unsigned short* wrow = Wob + (size_t)ecol * E_;
        floatx4 acc = {0.f, 0.f, 0.f, 0.f};
#pragma unroll
        for (int kc = 0; kc < 8; ++kc) {
            bf16x8 bf = *(const bf16x8*)(wrow + kc * 32 + quad * 8);
            acc = __builtin_amdgcn_mfma_f32_16x16x32_bf16(af[kc], bf, acc, 0, 0, 0);
        }
        float bias = bo[ecol];
        size_t base = (size_t)(mbase + quad * 4) * E_ + ecol;
#pragma unroll
        for (int r = 0; r < 4; ++r)
            out[base + (size_t)r * E_] = acc[r] + bias;
    }
}

extern "C" void kernel_launch(void* const* d_in, const int* in_sizes, int n_in,
                              void* d_out, int out_size, void* d_ws, size_t ws_size,
                              hipStream_t stream) {
    const float* hs   = (const float*)d_in[0];
    const float* oq   = (const float*)d_in[1];
    const float* mask = (const float*)d_in[2];
    const float* Wq   = (const float*)d_in[3];
    const float* bq   = (const float*)d_in[4];
    const float* Wk   = (const float*)d_in[5];
    const float* bk   = (const float*)d_in[6];
    const float* Wv   = (const float*)d_in[7];
    const float* bv   = (const float*)d_in[8];
    const float* Wo   = (const float*)d_in[9];
    const float* bo   = (const float*)d_in[10];
    float* out = (float*)d_out;

    const size_t nBHTD = (size_t)B_ * H_ * T_ * DH_;   // 4,194,304 elems
    unsigned short* Qw    = (unsigned short*)d_ws;
    unsigned short* Kw    = Qw + nBHTD;
    unsigned short* Vtw   = Kw + nBHTD;
    unsigned short* attnw = Vtw + nBHTD;               // 4 x 8 MB
    unsigned short* Wpack = attnw + nBHTD;             // + 512 KB
    int* mask_nz = (int*)(Wpack + 4 * 65536);

    prepack_kernel<<<128, 256, 0, stream>>>(Wq, Wk, Wv, Wo, Wpack, mask_nz);
    qkvmask_kernel<<<1536 + 2048, 256, 0, stream>>>(
        hs, oq, Wpack, bq, bk, bv, Qw, Kw, Vtw, (const int*)mask, mask_nz);
    attn_kernel<<<B_ * H_ * (T_ / 128), 256, 0, stream>>>(Qw, Kw, Vtw, mask, mask_nz, attnw);
    oproj_kernel<<<(B_ * T_) / 16, 256, 0, stream>>>(attnw, Wpack + 3 * 65536, bo, out);
}

// Round 9
// 362.751 us; speedup vs baseline: 1.2245x; 1.2245x over previous
//
#include <hip/hip_runtime.h>

#define B_ 8
#define T_ 2048
#define E_ 256
#define H_ 8
#define DH_ 32
#define SCALING_ 0.17677669529663687f   // 1/sqrt(32)
#define LOG2E_ 1.4426950408889634f
// Q is pre-scaled by SCALING*log2(e): scores exit QK in log2 domain -> hw exp2
#define QSCALE_ (SCALING_ * LOG2E_)

typedef short bf16x8 __attribute__((ext_vector_type(8)));   // 8 bf16 in 4 VGPRs
typedef float floatx4 __attribute__((ext_vector_type(4)));

__device__ __forceinline__ unsigned short f2bf(float f) {
    union { float f; unsigned u; } v; v.f = f;
    unsigned r = v.u + 0x7FFFu + ((v.u >> 16) & 1u);   // RNE
    return (unsigned short)(r >> 16);
}

// pack 2 f32 -> 2 bf16 (round-half-up) in 3 VALU: add, add, v_perm_b32
__device__ __forceinline__ unsigned pk2(float a, float b) {
    union { float f; unsigned u; } ua, ub;
    ua.f = a; ub.f = b;
    return __builtin_amdgcn_perm(ub.u + 0x8000u, ua.u + 0x8000u, 0x07060302u);
}

__device__ __forceinline__ float fexp2(float x) {
#if __has_builtin(__builtin_amdgcn_exp2f)
    return __builtin_amdgcn_exp2f(x);
#else
    return exp2f(x);
#endif
}

__device__ __forceinline__ bf16x8 pack8(float4 a, float4 b) {
    bf16x8 o;
    o[0] = (short)f2bf(a.x); o[1] = (short)f2bf(a.y);
    o[2] = (short)f2bf(a.z); o[3] = (short)f2bf(a.w);
    o[4] = (short)f2bf(b.x); o[5] = (short)f2bf(b.y);
    o[6] = (short)f2bf(b.z); o[7] = (short)f2bf(b.w);
    return o;
}

// ---------------------------------------------------------------------------
// Kernel 0: weight prepack fp32 -> bf16 (tiny: 128 blocks).
// Also zeroes mask_nz (replaces the separate hipMemsetAsync dispatch).
// ---------------------------------------------------------------------------
__global__ __launch_bounds__(256) void prepack_kernel(
    const float* __restrict__ Wq, const float* __restrict__ Wk,
    const float* __restrict__ Wv, const float* __restrict__ Wo,
    unsigned short* __restrict__ Wpack, int* __restrict__ mask_nz) {
    if (blockIdx.x == 0 && threadIdx.x == 0) *mask_nz = 0;
    int idx = blockIdx.x * 256 + threadIdx.x;   // 32768 threads
    int m = idx >> 13;                           // matrix id 0..3
    int e = (idx & 8191) * 8;
    const float* W = (m == 0) ? Wq : (m == 1) ? Wk : (m == 2) ? Wv : Wo;
    float4 a = ((const float4*)(W + e))[0];
    float4 b = ((const float4*)(W + e))[1];
    *(bf16x8*)(Wpack + (size_t)m * 65536 + e) = pack8(a, b);
}

// ---------------------------------------------------------------------------
// Kernel 1: QKV projection (blocks 0..1535) FUSED with mask nonzero check
// (blocks 1536..3583). mask_nz pre-zeroed by prepack_kernel.
// R9: MFMA operand order SWAPPED in both GEMM paths so the C-fragment's reg
// index r walks CONSECUTIVE output columns (Q/K: ecol = nt*16+quad*4+r;
// V: t = tbase+hgrp*16+quad*4+r). Epilogue becomes 2 x ushort4 (8 B) stores
// per tile-quarter instead of 8 scalar 2 B stores (4x fewer store instrs).
// Same GEMM (D = W·X^T is the transposed read of X·W^T), verified against
// C/D layout col=lane&15, row=quad*4+reg.
// ---------------------------------------------------------------------------
__global__ __launch_bounds__(256, 4) void qkvmask_kernel(
    const float* __restrict__ hs, const float* __restrict__ oq,
    const unsigned short* __restrict__ Wpack,
    const float* __restrict__ bq, const float* __restrict__ bk,
    const float* __restrict__ bv,
    unsigned short* __restrict__ Qw, unsigned short* __restrict__ Kw,
    unsigned short* __restrict__ Vtw,
    const int* __restrict__ mask, int* __restrict__ mask_nz) {
    if (blockIdx.x >= 1536) {
        // ---- mask scan: 2048 blocks, grid-stride int4 OR ----
        const size_t n4 = (size_t)B_ * T_ * T_ / 4;   // 8,388,608 int4
        size_t gid = (size_t)(blockIdx.x - 1536) * 256 + threadIdx.x;
        int acc = 0;
        for (size_t i = gid; i < n4; i += (size_t)2048 * 256) {
            int4 v = ((const int4*)mask)[i];
            acc |= v.x | v.y | v.z | v.w;
        }
        if (__builtin_amdgcn_ballot_w64(acc != 0)) {
            if ((threadIdx.x & 63) == 0) atomicOr(mask_nz, 1);
        }
        return;
    }
    __shared__ __align__(16) unsigned short sX[32][264];
    const int mat = blockIdx.x >> 9;          // 0=Q, 1=K, 2=V
    const int mbase = (blockIdx.x & 511) * 32;
    const int b = mbase >> 11, tbase = mbase & 2047;
    const int tid = threadIdx.x;

#pragma unroll
    for (int i = 0; i < 8; ++i) {
        int idx = tid + i * 256;
        int row = idx >> 6, c4 = idx & 63;
        float4 hv = ((const float4*)(hs + (size_t)(mbase + row) * E_))[c4];
        if (mat < 2) {
            float4 ov = ((const float4*)(oq + (size_t)(mbase + row) * E_))[c4];
            hv.x += ov.x; hv.y += ov.y; hv.z += ov.z; hv.w += ov.w;
        }
        ushort4 pb;
        pb.x = f2bf(hv.x); pb.y = f2bf(hv.y); pb.z = f2bf(hv.z); pb.w = f2bf(hv.w);
        *(ushort4*)&sX[row][c4 * 4] = pb;
    }
    __syncthreads();

    const int wave = tid >> 6, lane = tid & 63;
    const int quad = lane >> 4, m16 = lane & 15;
    const unsigned short* W = Wpack + (size_t)mat * 65536;

    bf16x8 xf[2][8];
#pragma unroll
    for (int hgrp = 0; hgrp < 2; ++hgrp)
#pragma unroll
        for (int kc = 0; kc < 8; ++kc)
            xf[hgrp][kc] = *(const bf16x8*)&sX[hgrp * 16 + m16][kc * 32 + quad * 8];

    if (mat < 2) {
        const float* bias = (mat == 0) ? bq : bk;
        unsigned short* Out = (mat == 0) ? Qw : Kw;
#pragma unroll
        for (int i = 0; i < 4; ++i) {
            int nt = wave * 4 + i;
            int ecol = nt * 16 + m16;                 // W row this lane loads
            const unsigned short* wrow = W + (size_t)ecol * E_;
            floatx4 acc0 = {0.f, 0.f, 0.f, 0.f};
            floatx4 acc1 = {0.f, 0.f, 0.f, 0.f};
#pragma unroll
            for (int kc = 0; kc < 8; ++kc) {
                bf16x8 bf = *(const bf16x8*)(wrow + kc * 32 + quad * 8);
                // swapped: A=W-frag, B=X-frag -> D[ecol][t]
                acc0 = __builtin_amdgcn_mfma_f32_16x16x32_bf16(bf, xf[0][kc], acc0, 0, 0, 0);
                acc1 = __builtin_amdgcn_mfma_f32_16x16x32_bf16(bf, xf[1][kc], acc1, 0, 0, 0);
            }
            // lane holds ecol = nt*16 + quad*4 + r (consecutive in r), t = tbase+hgrp*16+m16
            int ecol0 = nt * 16 + quad * 4;
            float4 bs = *(const float4*)(bias + ecol0);
            int h = ecol0 >> 5, dh0 = ecol0 & 31;
            size_t rowb = ((size_t)b * H_ + h) * T_ + tbase + m16;
            float v0[4], v1[4];
#pragma unroll
            for (int r = 0; r < 4; ++r) {
                float bsr = (r == 0) ? bs.x : (r == 1) ? bs.y : (r == 2) ? bs.z : bs.w;
                v0[r] = acc0[r] + bsr;
                v1[r] = acc1[r] + bsr;
                if (mat == 0) { v0[r] *= QSCALE_; v1[r] *= QSCALE_; }
            }
            ushort4 s0, s1;
            s0.x = f2bf(v0[0]); s0.y = f2bf(v0[1]); s0.z = f2bf(v0[2]); s0.w = f2bf(v0[3]);
            s1.x = f2bf(v1[0]); s1.y = f2bf(v1[1]); s1.z = f2bf(v1[2]); s1.w = f2bf(v1[3]);
            *(ushort4*)(Out + rowb * DH_ + dh0) = s0;
            *(ushort4*)(Out + (rowb + 16) * DH_ + dh0) = s1;
        }
    } else {
#pragma unroll
        for (int i = 0; i < 4; ++i) {
            int et = wave * 4 + i;
            int erow = et * 16 + m16;                 // W row this lane loads
            const unsigned short* wrow = W + (size_t)erow * E_;
            floatx4 acc0 = {0.f, 0.f, 0.f, 0.f};
            floatx4 acc1 = {0.f, 0.f, 0.f, 0.f};
#pragma unroll
            for (int kc = 0; kc < 8; ++kc) {
                bf16x8 wf = *(const bf16x8*)(wrow + kc * 32 + quad * 8);
                // swapped: A=X-frag, B=W-frag -> D[t][ev]
                acc0 = __builtin_amdgcn_mfma_f32_16x16x32_bf16(xf[0][kc], wf, acc0, 0, 0, 0);
                acc1 = __builtin_amdgcn_mfma_f32_16x16x32_bf16(xf[1][kc], wf, acc1, 0, 0, 0);
            }
            // lane holds ev = et*16 + m16, t = tbase + hgrp*16 + quad*4 + r (consecutive in r)
            int ev = et * 16 + m16;
            float bvv = bv[ev];
            size_t vb = (((size_t)b * H_ + (ev >> 5)) * DH_ + (ev & 31)) * T_;
            ushort4 s0, s1;
            s0.x = f2bf(acc0[0] + bvv); s0.y = f2bf(acc0[1] + bvv);
            s0.z = f2bf(acc0[2] + bvv); s0.w = f2bf(acc0[3] + bvv);
            s1.x = f2bf(acc1[0] + bvv); s1.y = f2bf(acc1[1] + bvv);
            s1.z = f2bf(acc1[2] + bvv); s1.w = f2bf(acc1[3] + bvv);
            *(ushort4*)(Vtw + vb + tbase + quad * 4) = s0;
            *(ushort4*)(Vtw + vb + tbase + 16 + quad * 4) = s1;
        }
    }
}

// ---------------------------------------------------------------------------
// Kernel 2: flash attention — EXACT R7 structure (verified 99.7 µs, VGPR 104,
// no spill): dual q-stream, 4-wave blocks, (256,2), V prefetched one kt ahead.
// R9 delta: s_setprio(1) around the QK and PV MFMA clusters. This structure
// (independent waves, no barriers, staggered phases) is the measured-useful
// setprio regime (m191: +4-7% attn); never cleanly A/B'd here before (R1-R4
// trials were confounded by spills). Tripwires: VGPR ~104, WRITE ~8 MB.
// ---------------------------------------------------------------------------
__global__ __launch_bounds__(256, 2) void attn_kernel(
    const unsigned short* __restrict__ Qw, const unsigned short* __restrict__ Kw,
    const unsigned short* __restrict__ Vtw, const float* __restrict__ mask,
    const int* __restrict__ mask_nz, unsigned short* __restrict__ attnw) {
    __shared__ __align__(16) unsigned short sPT[4][2][16][136];  // [wave][stream][q][key^swz]
    const int tid = threadIdx.x;
    const int wave = tid >> 6, lane = tid & 63;
    const int quad = lane >> 4, m16 = lane & 15;
    const int swz = (m16 & 8) * 4;            // 0 or 32 shorts (64 B granule)
    const int bh = blockIdx.x & 63, qt = blockIdx.x >> 6;   // bh%8==h -> XCD
    const int b = bh >> 3, h = bh & 7;
    const int qA = qt * 128 + wave * 32;
    const int qB = qA + 16;
    const int mnz = *mask_nz;

    bf16x8 qfragA = *(const bf16x8*)(Qw + ((size_t)bh * T_ + qA + m16) * DH_ + quad * 8);
    bf16x8 qfragB = *(const bf16x8*)(Qw + ((size_t)bh * T_ + qB + m16) * DH_ + quad * 8);
    const unsigned short* Kb = Kw + (size_t)bh * T_ * DH_;
    const unsigned short* Vb = Vtw + (size_t)bh * DH_ * T_;
    const float* MbA = mask + ((size_t)b * T_ + qA + m16) * T_ + quad * 4;
    const float* MbB = MbA + (size_t)16 * T_;

    floatx4 O0A = {0.f, 0.f, 0.f, 0.f}, O1A = {0.f, 0.f, 0.f, 0.f};
    floatx4 O0B = {0.f, 0.f, 0.f, 0.f}, O1B = {0.f, 0.f, 0.f, 0.f};
    floatx4 LA  = {0.f, 0.f, 0.f, 0.f}, LB  = {0.f, 0.f, 0.f, 0.f};  // l accumulators
    float mprevA = -1e30f, mprevB = -1e30f;
    const floatx4 zero = {0.f, 0.f, 0.f, 0.f};

    bf16x8 ones8;
#pragma unroll
    for (int i = 0; i < 8; ++i) ones8[i] = (short)0x3F80;   // bf16 1.0

    bf16x8 kf[8];
#pragma unroll
    for (int c = 0; c < 8; ++c)
        kf[c] = *(const bf16x8*)(Kb + (size_t)(c * 16 + m16) * DH_ + quad * 8);

    // V prefetch for kt=0: rows m16 and 16+m16, keys 0..127.
    bf16x8 vf0[4], vf1[4];
#pragma unroll
    for (int sb = 0; sb < 4; ++sb) {
        vf0[sb] = *(const bf16x8*)(Vb + (size_t)m16 * T_ + sb * 32 + quad * 8);
        vf1[sb] = *(const bf16x8*)(Vb + (size_t)(16 + m16) * T_ + sb * 32 + quad * 8);
    }

    for (int kt = 0; kt < 16; ++kt) {
        const int s0 = kt * 128;
#pragma unroll
        for (int hf = 0; hf < 2; ++hf) {
            const int cb = hf * 4;
            floatx4 scA[4], scB[4];
            __builtin_amdgcn_s_setprio(1);
#pragma unroll
            for (int c = 0; c < 4; ++c) {
                scA[c] = __builtin_amdgcn_mfma_f32_16x16x32_bf16(kf[cb + c], qfragA, zero, 0, 0, 0);
                scB[c] = __builtin_amdgcn_mfma_f32_16x16x32_bf16(kf[cb + c], qfragB, zero, 0, 0, 0);
            }
            __builtin_amdgcn_s_setprio(0);
            if (kt < 15) {
#pragma unroll
                for (int c = 0; c < 4; ++c)
                    kf[cb + c] = *(const bf16x8*)(
                        Kb + (size_t)(s0 + 128 + (cb + c) * 16 + m16) * DH_ + quad * 8);
            }
            if (!mnz) {
                // FAST PATH: raw exp2, pack, LDS. No stats, no adds.
#pragma unroll
                for (int c = 0; c < 4; ++c) {
                    float a0 = fexp2(scA[c][0]), a1 = fexp2(scA[c][1]);
                    float a2 = fexp2(scA[c][2]), a3 = fexp2(scA[c][3]);
                    float b0 = fexp2(scB[c][0]), b1 = fexp2(scB[c][1]);
                    float b2 = fexp2(scB[c][2]), b3 = fexp2(scB[c][3]);
                    uint2 wa = {pk2(a0, a1), pk2(a2, a3)};
                    uint2 wb = {pk2(b0, b1), pk2(b2, b3)};
                    int col = (((cb + c) * 16) ^ swz) + quad * 4;
                    *(uint2*)&sPT[wave][0][m16][col] = wa;
                    *(uint2*)&sPT[wave][1][m16][col] = wb;
                }
            } else {
                // SLOW PATH: online softmax in log2 domain; mask scaled by log2e.
#pragma unroll
                for (int c = 0; c < 4; ++c) {
                    float4 ma = *(const float4*)(MbA + s0 + (cb + c) * 16);
                    float4 mb = *(const float4*)(MbB + s0 + (cb + c) * 16);
                    scA[c][0] += ma.x * LOG2E_; scA[c][1] += ma.y * LOG2E_;
                    scA[c][2] += ma.z * LOG2E_; scA[c][3] += ma.w * LOG2E_;
                    scB[c][0] += mb.x * LOG2E_; scB[c][1] += mb.y * LOG2E_;
                    scB[c][2] += mb.z * LOG2E_; scB[c][3] += mb.w * LOG2E_;
                }
                float mlA = -1e30f, mlB = -1e30f;
#pragma unroll
                for (int c = 0; c < 4; ++c) {
                    mlA = fmaxf(fmaxf(fmaxf(scA[c][0], scA[c][1]), fmaxf(scA[c][2], scA[c][3])), mlA);
                    mlB = fmaxf(fmaxf(fmaxf(scB[c][0], scB[c][1]), fmaxf(scB[c][2], scB[c][3])), mlB);
                }
                mlA = fmaxf(mlA, __shfl_xor(mlA, 16, 64));
                mlA = fmaxf(mlA, __shfl_xor(mlA, 32, 64));
                mlB = fmaxf(mlB, __shfl_xor(mlB, 16, 64));
                mlB = fmaxf(mlB, __shfl_xor(mlB, 32, 64));
                float mnA = fmaxf(mprevA, mlA), mnB = fmaxf(mprevB, mlB);
                float alA = fexp2(mprevA - mnA), alB = fexp2(mprevB - mnB);
                mprevA = mnA; mprevB = mnB;
#pragma unroll
                for (int r = 0; r < 4; ++r) {
                    O0A[r] *= alA; O1A[r] *= alA; LA[r] *= alA;
                    O0B[r] *= alB; O1B[r] *= alB; LB[r] *= alB;
                }
#pragma unroll
                for (int c = 0; c < 4; ++c) {
                    float a0 = fexp2(scA[c][0] - mnA), a1 = fexp2(scA[c][1] - mnA);
                    float a2 = fexp2(scA[c][2] - mnA), a3 = fexp2(scA[c][3] - mnA);
                    float b0 = fexp2(scB[c][0] - mnB), b1 = fexp2(scB[c][1] - mnB);
                    float b2 = fexp2(scB[c][2] - mnB), b3 = fexp2(scB[c][3] - mnB);
                    uint2 wa = {pk2(a0, a1), pk2(a2, a3)};
                    uint2 wb = {pk2(b0, b1), pk2(b2, b3)};
                    int col = (((cb + c) * 16) ^ swz) + quad * 4;
                    *(uint2*)&sPT[wave][0][m16][col] = wa;
                    *(uint2*)&sPT[wave][1][m16][col] = wb;
                }
            }
        }
        // PV + l: O^T += V^T·P, L += 1^T·P (MFMA pipe), V in prefetched regs.
#pragma unroll
        for (int sb = 0; sb < 4; ++sb) {
            int col = ((sb * 32) ^ swz) + quad * 8;
            bf16x8 pbA = *(const bf16x8*)&sPT[wave][0][m16][col];
            bf16x8 pbB = *(const bf16x8*)&sPT[wave][1][m16][col];
            __builtin_amdgcn_s_setprio(1);
            O0A = __builtin_amdgcn_mfma_f32_16x16x32_bf16(vf0[sb], pbA, O0A, 0, 0, 0);
            O0B = __builtin_amdgcn_mfma_f32_16x16x32_bf16(vf0[sb], pbB, O0B, 0, 0, 0);
            O1A = __builtin_amdgcn_mfma_f32_16x16x32_bf16(vf1[sb], pbA, O1A, 0, 0, 0);
            O1B = __builtin_amdgcn_mfma_f32_16x16x32_bf16(vf1[sb], pbB, O1B, 0, 0, 0);
            LA  = __builtin_amdgcn_mfma_f32_16x16x32_bf16(ones8, pbA, LA, 0, 0, 0);
            LB  = __builtin_amdgcn_mfma_f32_16x16x32_bf16(ones8, pbB, LB, 0, 0, 0);
            __builtin_amdgcn_s_setprio(0);
        }
        // V prefetch for kt+1 — a full QK+exp2 phase of latency cover.
        if (kt < 15) {
#pragma unroll
            for (int sb = 0; sb < 4; ++sb) {
                vf0[sb] = *(const bf16x8*)(Vb + (size_t)m16 * T_ + s0 + 128 + sb * 32 + quad * 8);
                vf1[sb] = *(const bf16x8*)(Vb + (size_t)(16 + m16) * T_ + s0 + 128 + sb * 32 + quad * 8);
            }
        }
    }
    // LA/LB rows all hold l[q=m16] — no shuffles needed.
    float invA = 1.0f / LA[0], invB = 1.0f / LB[0];
    size_t obA = ((size_t)b * T_ + qA + m16) * E_ + h * DH_ + quad * 4;
    size_t obB = ((size_t)b * T_ + qB + m16) * E_ + h * DH_ + quad * 4;
    ushort4 sv;
    sv.x = f2bf(O0A[0] * invA); sv.y = f2bf(O0A[1] * invA);
    sv.z = f2bf(O0A[2] * invA); sv.w = f2bf(O0A[3] * invA);
    *(ushort4*)(attnw + obA) = sv;
    sv.x = f2bf(O1A[0] * invA); sv.y = f2bf(O1A[1] * invA);
    sv.z = f2bf(O1A[2] * invA); sv.w = f2bf(O1A[3] * invA);
    *(ushort4*)(attnw + obA + 16) = sv;
    sv.x = f2bf(O0B[0] * invB); sv.y = f2bf(O0B[1] * invB);
    sv.z = f2bf(O0B[2] * invB); sv.w = f2bf(O0B[3] * invB);
    *(ushort4*)(attnw + obB) = sv;
    sv.x = f2bf(O1B[0] * invB); sv.y = f2bf(O1B[1] * invB);
    sv.z = f2bf(O1B[2] * invB); sv.w = f2bf(O1B[3] * invB);
    *(ushort4*)(attnw + obB + 16) = sv;
}

// ---------------------------------------------------------------------------
// Kernel 3: output projection: out = attn @ Wo^T + bo  (fp32 out, bf16 weights)
// ---------------------------------------------------------------------------
__global__ __launch_bounds__(256, 4) void oproj_kernel(
    const unsigned short* __restrict__ attnw, const unsigned short* __restrict__ Wob,
    const float* __restrict__ bo, float* __restrict__ out) {
    __shared__ __align__(16) unsigned short sA[16][264];
    const int tid = threadIdx.x;
    const int mbase = blockIdx.x * 16;
#pragma unroll
    for (int i = 0; i < 4; ++i) {
        int idx = tid + i * 256;
        int row = idx >> 6, c4 = idx & 63;
        const ushort4 a = ((const ushort4*)(attnw + (size_t)(mbase + row) * E_))[c4];
        *(ushort4*)&sA[row][c4 * 4] = a;
    }
    __syncthreads();
    const int wave = tid >> 6, lane = tid & 63;
    const int quad = lane >> 4, m16 = lane & 15;

    bf16x8 af[8];
#pragma unroll
    for (int kc = 0; kc < 8; ++kc)
        af[kc] = *(const bf16x8*)&sA[m16][kc * 32 + quad * 8];

#pragma unroll
    for (int i = 0; i < 4; ++i) {
        int nt = wave * 4 + i;
        int ecol = nt * 16 + m16;
        const unsigned short* wrow = Wob + (size_t)ecol * E_;
        floatx4 acc = {0.f, 0.f, 0.f, 0.f};
#pragma unroll
        for (int kc = 0; kc < 8; ++kc) {
            bf16x8 bf = *(const bf16x8*)(wrow + kc * 32 + quad * 8);
            acc = __builtin_amdgcn_mfma_f32_16x16x32_bf16(af[kc], bf, acc, 0, 0, 0);
        }
        float bias = bo[ecol];
        size_t base = (size_t)(mbase + quad * 4) * E_ + ecol;
#pragma unroll
        for (int r = 0; r < 4; ++r)
            out[base + (size_t)r * E_] = acc[r] + bias;
    }
}

extern "C" void kernel_launch(void* const* d_in, const int* in_sizes, int n_in,
                              void* d_out, int out_size, void* d_ws, size_t ws_size,
                              hipStream_t stream) {
    const float* hs   = (const float*)d_in[0];
    const float* oq   = (const float*)d_in[1];
    const float* mask = (const float*)d_in[2];
    const float* Wq   = (const float*)d_in[3];
    const float* bq   = (const float*)d_in[4];
    const float* Wk   = (const float*)d_in[5];
    const float* bk   = (const float*)d_in[6];
    const float* Wv   = (const float*)d_in[7];
    const float* bv   = (const float*)d_in[8];
    const float* Wo   = (const float*)d_in[9];
    const float* bo   = (const float*)d_in[10];
    float* out = (float*)d_out;

    const size_t nBHTD = (size_t)B_ * H_ * T_ * DH_;   // 4,194,304 elems
    unsigned short* Qw    = (unsigned short*)d_ws;
    unsigned short* Kw    = Qw + nBHTD;
    unsigned short* Vtw   = Kw + nBHTD;
    unsigned short* attnw = Vtw + nBHTD;               // 4 x 8 MB
    unsigned short* Wpack = attnw + nBHTD;             // + 512 KB
    int* mask_nz = (int*)(Wpack + 4 * 65536);

    prepack_kernel<<<128, 256, 0, stream>>>(Wq, Wk, Wv, Wo, Wpack, mask_nz);
    qkvmask_kernel<<<1536 + 2048, 256, 0, stream>>>(
        hs, oq, Wpack, bq, bk, bv, Qw, Kw, Vtw, (const int*)mask, mask_nz);
    attn_kernel<<<B_ * H_ * (T_ / 128), 256, 0, stream>>>(Qw, Kw, Vtw, mask, mask_nz, attnw);
    oproj_kernel<<<(B_ * T_) / 16, 256, 0, stream>>>(attnw, Wpack + 3 * 65536, bo, out);
}

// Round 11
// 360.665 us; speedup vs baseline: 1.2316x; 1.0058x over previous
//
#include <hip/hip_runtime.h>

#define B_ 8
#define T_ 2048
#define E_ 256
#define H_ 8
#define DH_ 32
#define SCALING_ 0.17677669529663687f   // 1/sqrt(32)
#define LOG2E_ 1.4426950408889634f
// Q is pre-scaled by SCALING*log2(e): scores exit QK in log2 domain -> hw exp2
#define QSCALE_ (SCALING_ * LOG2E_)

typedef short bf16x8 __attribute__((ext_vector_type(8)));   // 8 bf16 in 4 VGPRs
typedef float floatx4 __attribute__((ext_vector_type(4)));
typedef int intx4 __attribute__((ext_vector_type(4)));      // native vec for nt-load

__device__ __forceinline__ unsigned short f2bf(float f) {
    union { float f; unsigned u; } v; v.f = f;
    unsigned r = v.u + 0x7FFFu + ((v.u >> 16) & 1u);   // RNE
    return (unsigned short)(r >> 16);
}

// pack 2 f32 -> 2 bf16 (round-half-up) in 3 VALU: add, add, v_perm_b32
__device__ __forceinline__ unsigned pk2(float a, float b) {
    union { float f; unsigned u; } ua, ub;
    ua.f = a; ub.f = b;
    return __builtin_amdgcn_perm(ub.u + 0x8000u, ua.u + 0x8000u, 0x07060302u);
}

__device__ __forceinline__ float fexp2(float x) {
#if __has_builtin(__builtin_amdgcn_exp2f)
    return __builtin_amdgcn_exp2f(x);
#else
    return exp2f(x);
#endif
}

__device__ __forceinline__ bf16x8 pack8(float4 a, float4 b) {
    bf16x8 o;
    o[0] = (short)f2bf(a.x); o[1] = (short)f2bf(a.y);
    o[2] = (short)f2bf(a.z); o[3] = (short)f2bf(a.w);
    o[4] = (short)f2bf(b.x); o[5] = (short)f2bf(b.y);
    o[6] = (short)f2bf(b.z); o[7] = (short)f2bf(b.w);
    return o;
}

// ---------------------------------------------------------------------------
// Kernel 0: weight prepack fp32 -> bf16 (tiny: 128 blocks).
// Also zeroes mask_nz (replaces the separate hipMemsetAsync dispatch).
// ---------------------------------------------------------------------------
__global__ __launch_bounds__(256) void prepack_kernel(
    const float* __restrict__ Wq, const float* __restrict__ Wk,
    const float* __restrict__ Wv, const float* __restrict__ Wo,
    unsigned short* __restrict__ Wpack, int* __restrict__ mask_nz) {
    if (blockIdx.x == 0 && threadIdx.x == 0) *mask_nz = 0;
    int idx = blockIdx.x * 256 + threadIdx.x;   // 32768 threads
    int m = idx >> 13;                           // matrix id 0..3
    int e = (idx & 8191) * 8;
    const float* W = (m == 0) ? Wq : (m == 1) ? Wk : (m == 2) ? Wv : Wo;
    float4 a = ((const float4*)(W + e))[0];
    float4 b = ((const float4*)(W + e))[1];
    *(bf16x8*)(Wpack + (size_t)m * 65536 + e) = pack8(a, b);
}

// ---------------------------------------------------------------------------
// Kernel 1: QKV projection (blocks 0..1535) FUSED with mask nonzero check
// (blocks 1536..3583). mask_nz pre-zeroed by prepack_kernel; -0.0 -> slow path.
// R11 (= R10 intent, compile-fixed): scan loads NON-TEMPORAL via native
// ext_vector_type int4 (__builtin_nontemporal_load rejects HIP_vector_type).
// The 134 MB mask stream otherwise evicts Q/K/V (24 MB, needed by attn right
// after) from L2/L3 — attn's 13.8 MB FETCH shows the re-fetch.
// ---------------------------------------------------------------------------
__global__ __launch_bounds__(256, 4) void qkvmask_kernel(
    const float* __restrict__ hs, const float* __restrict__ oq,
    const unsigned short* __restrict__ Wpack,
    const float* __restrict__ bq, const float* __restrict__ bk,
    const float* __restrict__ bv,
    unsigned short* __restrict__ Qw, unsigned short* __restrict__ Kw,
    unsigned short* __restrict__ Vtw,
    const int* __restrict__ mask, int* __restrict__ mask_nz) {
    if (blockIdx.x >= 1536) {
        // ---- mask scan: 2048 blocks, grid-stride, non-temporal intx4 OR ----
        const size_t n4 = (size_t)B_ * T_ * T_ / 4;   // 8,388,608 intx4
        size_t gid = (size_t)(blockIdx.x - 1536) * 256 + threadIdx.x;
        int acc = 0;
        const intx4* m4 = (const intx4*)mask;
        for (size_t i = gid; i < n4; i += (size_t)2048 * 256) {
            intx4 v = __builtin_nontemporal_load(m4 + i);
            acc |= v.x | v.y | v.z | v.w;
        }
        if (__builtin_amdgcn_ballot_w64(acc != 0)) {
            if ((threadIdx.x & 63) == 0) atomicOr(mask_nz, 1);
        }
        return;
    }
    __shared__ __align__(16) unsigned short sX[32][264];
    const int mat = blockIdx.x >> 9;          // 0=Q, 1=K, 2=V
    const int mbase = (blockIdx.x & 511) * 32;
    const int b = mbase >> 11, tbase = mbase & 2047;
    const int tid = threadIdx.x;

#pragma unroll
    for (int i = 0; i < 8; ++i) {
        int idx = tid + i * 256;
        int row = idx >> 6, c4 = idx & 63;
        float4 hv = ((const float4*)(hs + (size_t)(mbase + row) * E_))[c4];
        if (mat < 2) {
            float4 ov = ((const float4*)(oq + (size_t)(mbase + row) * E_))[c4];
            hv.x += ov.x; hv.y += ov.y; hv.z += ov.z; hv.w += ov.w;
        }
        ushort4 pb;
        pb.x = f2bf(hv.x); pb.y = f2bf(hv.y); pb.z = f2bf(hv.z); pb.w = f2bf(hv.w);
        *(ushort4*)&sX[row][c4 * 4] = pb;
    }
    __syncthreads();

    const int wave = tid >> 6, lane = tid & 63;
    const int quad = lane >> 4, m16 = lane & 15;
    const unsigned short* W = Wpack + (size_t)mat * 65536;

    bf16x8 xf[2][8];
#pragma unroll
    for (int hgrp = 0; hgrp < 2; ++hgrp)
#pragma unroll
        for (int kc = 0; kc < 8; ++kc)
            xf[hgrp][kc] = *(const bf16x8*)&sX[hgrp * 16 + m16][kc * 32 + quad * 8];

    if (mat < 2) {
        const float* bias = (mat == 0) ? bq : bk;
        unsigned short* Out = (mat == 0) ? Qw : Kw;
#pragma unroll
        for (int i = 0; i < 4; ++i) {
            int nt = wave * 4 + i;
            int ecol = nt * 16 + m16;
            const unsigned short* wrow = W + (size_t)ecol * E_;
            floatx4 acc0 = {0.f, 0.f, 0.f, 0.f};
            floatx4 acc1 = {0.f, 0.f, 0.f, 0.f};
#pragma unroll
            for (int kc = 0; kc < 8; ++kc) {
                bf16x8 bf = *(const bf16x8*)(wrow + kc * 32 + quad * 8);
                acc0 = __builtin_amdgcn_mfma_f32_16x16x32_bf16(xf[0][kc], bf, acc0, 0, 0, 0);
                acc1 = __builtin_amdgcn_mfma_f32_16x16x32_bf16(xf[1][kc], bf, acc1, 0, 0, 0);
            }
            float bs = bias[ecol];
            int h = ecol >> 5, dh = ecol & 31;
            size_t base0 = (((size_t)b * H_ + h) * T_ + (tbase + quad * 4)) * DH_ + dh;
            size_t base1 = base0 + (size_t)16 * DH_;
#pragma unroll
            for (int r = 0; r < 4; ++r) {
                float v0 = acc0[r] + bs, v1 = acc1[r] + bs;
                if (mat == 0) { v0 *= QSCALE_; v1 *= QSCALE_; }
                Out[base0 + (size_t)r * DH_] = f2bf(v0);
                Out[base1 + (size_t)r * DH_] = f2bf(v1);
            }
        }
    } else {
#pragma unroll
        for (int i = 0; i < 4; ++i) {
            int et = wave * 4 + i;
            int erow = et * 16 + m16;
            const unsigned short* wrow = W + (size_t)erow * E_;
            floatx4 acc0 = {0.f, 0.f, 0.f, 0.f};
            floatx4 acc1 = {0.f, 0.f, 0.f, 0.f};
#pragma unroll
            for (int kc = 0; kc < 8; ++kc) {
                bf16x8 wf = *(const bf16x8*)(wrow + kc * 32 + quad * 8);
                acc0 = __builtin_amdgcn_mfma_f32_16x16x32_bf16(wf, xf[0][kc], acc0, 0, 0, 0);
                acc1 = __builtin_amdgcn_mfma_f32_16x16x32_bf16(wf, xf[1][kc], acc1, 0, 0, 0);
            }
            int t0 = tbase + m16, t1 = t0 + 16;
#pragma unroll
            for (int r = 0; r < 4; ++r) {
                int ev = et * 16 + quad * 4 + r;
                int h = ev >> 5, dh = ev & 31;
                size_t vb = (((size_t)b * H_ + h) * DH_ + dh) * T_;
                Vtw[vb + t0] = f2bf(acc0[r] + bv[ev]);
                Vtw[vb + t1] = f2bf(acc1[r] + bv[ev]);
            }
        }
    }
}

// ---------------------------------------------------------------------------
// Kernel 2: flash attention — EXACT R7 (verified best: 99.7 µs attn, 356 µs
// total, VGPR 104, no spill). Dual q-stream, 4-wave blocks, (256,2) so the
// VGPR half of the unified budget is 128 (cap/2 law, verified R7), V
// prefetched one kt ahead in registers. setprio dropped (R9: neutral).
// All pipelining/occupancy variants measured worse (R1-R8 ledger).
// ---------------------------------------------------------------------------
__global__ __launch_bounds__(256, 2) void attn_kernel(
    const unsigned short* __restrict__ Qw, const unsigned short* __restrict__ Kw,
    const unsigned short* __restrict__ Vtw, const float* __restrict__ mask,
    const int* __restrict__ mask_nz, unsigned short* __restrict__ attnw) {
    __shared__ __align__(16) unsigned short sPT[4][2][16][136];  // [wave][stream][q][key^swz]
    const int tid = threadIdx.x;
    const int wave = tid >> 6, lane = tid & 63;
    const int quad = lane >> 4, m16 = lane & 15;
    const int swz = (m16 & 8) * 4;            // 0 or 32 shorts (64 B granule)
    const int bh = blockIdx.x & 63, qt = blockIdx.x >> 6;   // bh%8==h -> XCD
    const int b = bh >> 3, h = bh & 7;
    const int qA = qt * 128 + wave * 32;
    const int qB = qA + 16;
    const int mnz = *mask_nz;

    bf16x8 qfragA = *(const bf16x8*)(Qw + ((size_t)bh * T_ + qA + m16) * DH_ + quad * 8);
    bf16x8 qfragB = *(const bf16x8*)(Qw + ((size_t)bh * T_ + qB + m16) * DH_ + quad * 8);
    const unsigned short* Kb = Kw + (size_t)bh * T_ * DH_;
    const unsigned short* Vb = Vtw + (size_t)bh * DH_ * T_;
    const float* MbA = mask + ((size_t)b * T_ + qA + m16) * T_ + quad * 4;
    const float* MbB = MbA + (size_t)16 * T_;

    floatx4 O0A = {0.f, 0.f, 0.f, 0.f}, O1A = {0.f, 0.f, 0.f, 0.f};
    floatx4 O0B = {0.f, 0.f, 0.f, 0.f}, O1B = {0.f, 0.f, 0.f, 0.f};
    floatx4 LA  = {0.f, 0.f, 0.f, 0.f}, LB  = {0.f, 0.f, 0.f, 0.f};  // l accumulators
    float mprevA = -1e30f, mprevB = -1e30f;
    const floatx4 zero = {0.f, 0.f, 0.f, 0.f};

    bf16x8 ones8;
#pragma unroll
    for (int i = 0; i < 8; ++i) ones8[i] = (short)0x3F80;   // bf16 1.0

    bf16x8 kf[8];
#pragma unroll
    for (int c = 0; c < 8; ++c)
        kf[c] = *(const bf16x8*)(Kb + (size_t)(c * 16 + m16) * DH_ + quad * 8);

    // V prefetch for kt=0: rows m16 and 16+m16, keys 0..127.
    bf16x8 vf0[4], vf1[4];
#pragma unroll
    for (int sb = 0; sb < 4; ++sb) {
        vf0[sb] = *(const bf16x8*)(Vb + (size_t)m16 * T_ + sb * 32 + quad * 8);
        vf1[sb] = *(const bf16x8*)(Vb + (size_t)(16 + m16) * T_ + sb * 32 + quad * 8);
    }

    for (int kt = 0; kt < 16; ++kt) {
        const int s0 = kt * 128;
#pragma unroll
        for (int hf = 0; hf < 2; ++hf) {
            const int cb = hf * 4;
            floatx4 scA[4], scB[4];
#pragma unroll
            for (int c = 0; c < 4; ++c) {
                scA[c] = __builtin_amdgcn_mfma_f32_16x16x32_bf16(kf[cb + c], qfragA, zero, 0, 0, 0);
                scB[c] = __builtin_amdgcn_mfma_f32_16x16x32_bf16(kf[cb + c], qfragB, zero, 0, 0, 0);
            }
            if (kt < 15) {
#pragma unroll
                for (int c = 0; c < 4; ++c)
                    kf[cb + c] = *(const bf16x8*)(
                        Kb + (size_t)(s0 + 128 + (cb + c) * 16 + m16) * DH_ + quad * 8);
            }
            if (!mnz) {
                // FAST PATH: raw exp2, pack, LDS. No stats, no adds.
#pragma unroll
                for (int c = 0; c < 4; ++c) {
                    float a0 = fexp2(scA[c][0]), a1 = fexp2(scA[c][1]);
                    float a2 = fexp2(scA[c][2]), a3 = fexp2(scA[c][3]);
                    float b0 = fexp2(scB[c][0]), b1 = fexp2(scB[c][1]);
                    float b2 = fexp2(scB[c][2]), b3 = fexp2(scB[c][3]);
                    uint2 wa = {pk2(a0, a1), pk2(a2, a3)};
                    uint2 wb = {pk2(b0, b1), pk2(b2, b3)};
                    int col = (((cb + c) * 16) ^ swz) + quad * 4;
                    *(uint2*)&sPT[wave][0][m16][col] = wa;
                    *(uint2*)&sPT[wave][1][m16][col] = wb;
                }
            } else {
                // SLOW PATH: online softmax in log2 domain; mask scaled by log2e.
#pragma unroll
                for (int c = 0; c < 4; ++c) {
                    float4 ma = *(const float4*)(MbA + s0 + (cb + c) * 16);
                    float4 mb = *(const float4*)(MbB + s0 + (cb + c) * 16);
                    scA[c][0] += ma.x * LOG2E_; scA[c][1] += ma.y * LOG2E_;
                    scA[c][2] += ma.z * LOG2E_; scA[c][3] += ma.w * LOG2E_;
                    scB[c][0] += mb.x * LOG2E_; scB[c][1] += mb.y * LOG2E_;
                    scB[c][2] += mb.z * LOG2E_; scB[c][3] += mb.w * LOG2E_;
                }
                float mlA = -1e30f, mlB = -1e30f;
#pragma unroll
                for (int c = 0; c < 4; ++c) {
                    mlA = fmaxf(fmaxf(fmaxf(scA[c][0], scA[c][1]), fmaxf(scA[c][2], scA[c][3])), mlA);
                    mlB = fmaxf(fmaxf(fmaxf(scB[c][0], scB[c][1]), fmaxf(scB[c][2], scB[c][3])), mlB);
                }
                mlA = fmaxf(mlA, __shfl_xor(mlA, 16, 64));
                mlA = fmaxf(mlA, __shfl_xor(mlA, 32, 64));
                mlB = fmaxf(mlB, __shfl_xor(mlB, 16, 64));
                mlB = fmaxf(mlB, __shfl_xor(mlB, 32, 64));
                float mnA = fmaxf(mprevA, mlA), mnB = fmaxf(mprevB, mlB);
                float alA = fexp2(mprevA - mnA), alB = fexp2(mprevB - mnB);
                mprevA = mnA; mprevB = mnB;
#pragma unroll
                for (int r = 0; r < 4; ++r) {
                    O0A[r] *= alA; O1A[r] *= alA; LA[r] *= alA;
                    O0B[r] *= alB; O1B[r] *= alB; LB[r] *= alB;
                }
#pragma unroll
                for (int c = 0; c < 4; ++c) {
                    float a0 = fexp2(scA[c][0] - mnA), a1 = fexp2(scA[c][1] - mnA);
                    float a2 = fexp2(scA[c][2] - mnA), a3 = fexp2(scA[c][3] - mnA);
                    float b0 = fexp2(scB[c][0] - mnB), b1 = fexp2(scB[c][1] - mnB);
                    float b2 = fexp2(scB[c][2] - mnB), b3 = fexp2(scB[c][3] - mnB);
                    uint2 wa = {pk2(a0, a1), pk2(a2, a3)};
                    uint2 wb = {pk2(b0, b1), pk2(b2, b3)};
                    int col = (((cb + c) * 16) ^ swz) + quad * 4;
                    *(uint2*)&sPT[wave][0][m16][col] = wa;
                    *(uint2*)&sPT[wave][1][m16][col] = wb;
                }
            }
        }
        // PV + l: O^T += V^T·P, L += 1^T·P (MFMA pipe), V in prefetched regs.
#pragma unroll
        for (int sb = 0; sb < 4; ++sb) {
            int col = ((sb * 32) ^ swz) + quad * 8;
            bf16x8 pbA = *(const bf16x8*)&sPT[wave][0][m16][col];
            bf16x8 pbB = *(const bf16x8*)&sPT[wave][1][m16][col];
            O0A = __builtin_amdgcn_mfma_f32_16x16x32_bf16(vf0[sb], pbA, O0A, 0, 0, 0);
            O0B = __builtin_amdgcn_mfma_f32_16x16x32_bf16(vf0[sb], pbB, O0B, 0, 0, 0);
            O1A = __builtin_amdgcn_mfma_f32_16x16x32_bf16(vf1[sb], pbA, O1A, 0, 0, 0);
            O1B = __builtin_amdgcn_mfma_f32_16x16x32_bf16(vf1[sb], pbB, O1B, 0, 0, 0);
            LA  = __builtin_amdgcn_mfma_f32_16x16x32_bf16(ones8, pbA, LA, 0, 0, 0);
            LB  = __builtin_amdgcn_mfma_f32_16x16x32_bf16(ones8, pbB, LB, 0, 0, 0);
        }
        // V prefetch for kt+1 — a full QK+exp2 phase of latency cover.
        if (kt < 15) {
#pragma unroll
            for (int sb = 0; sb < 4; ++sb) {
                vf0[sb] = *(const bf16x8*)(Vb + (size_t)m16 * T_ + s0 + 128 + sb * 32 + quad * 8);
                vf1[sb] = *(const bf16x8*)(Vb + (size_t)(16 + m16) * T_ + s0 + 128 + sb * 32 + quad * 8);
            }
        }
    }
    // LA/LB rows all hold l[q=m16] — no shuffles needed.
    float invA = 1.0f / LA[0], invB = 1.0f / LB[0];
    size_t obA = ((size_t)b * T_ + qA + m16) * E_ + h * DH_ + quad * 4;
    size_t obB = ((size_t)b * T_ + qB + m16) * E_ + h * DH_ + quad * 4;
    ushort4 sv;
    sv.x = f2bf(O0A[0] * invA); sv.y = f2bf(O0A[1] * invA);
    sv.z = f2bf(O0A[2] * invA); sv.w = f2bf(O0A[3] * invA);
    *(ushort4*)(attnw + obA) = sv;
    sv.x = f2bf(O1A[0] * invA); sv.y = f2bf(O1A[1] * invA);
    sv.z = f2bf(O1A[2] * invA); sv.w = f2bf(O1A[3] * invA);
    *(ushort4*)(attnw + obA + 16) = sv;
    sv.x = f2bf(O0B[0] * invB); sv.y = f2bf(O0B[1] * invB);
    sv.z = f2bf(O0B[2] * invB); sv.w = f2bf(O0B[3] * invB);
    *(ushort4*)(attnw + obB) = sv;
    sv.x = f2bf(O1B[0] * invB); sv.y = f2bf(O1B[1] * invB);
    sv.z = f2bf(O1B[2] * invB); sv.w = f2bf(O1B[3] * invB);
    *(ushort4*)(attnw + obB + 16) = sv;
}

// ---------------------------------------------------------------------------
// Kernel 3: output projection: out = attn @ Wo^T + bo  (fp32 out, bf16 weights)
// ---------------------------------------------------------------------------
__global__ __launch_bounds__(256, 4) void oproj_kernel(
    const unsigned short* __restrict__ attnw, const unsigned short* __restrict__ Wob,
    const float* __restrict__ bo, float* __restrict__ out) {
    __shared__ __align__(16) unsigned short sA[16][264];
    const int tid = threadIdx.x;
    const int mbase = blockIdx.x * 16;
#pragma unroll
    for (int i = 0; i < 4; ++i) {
        int idx = tid + i * 256;
        int row = idx >> 6, c4 = idx & 63;
        const ushort4 a = ((const ushort4*)(attnw + (size_t)(mbase + row) * E_))[c4];
        *(ushort4*)&sA[row][c4 * 4] = a;
    }
    __syncthreads();
    const int wave = tid >> 6, lane = tid & 63;
    const int quad = lane >> 4, m16 = lane & 15;

    bf16x8 af[8];
#pragma unroll
    for (int kc = 0; kc < 8; ++kc)
        af[kc] = *(const bf16x8*)&sA[m16][kc * 32 + quad * 8];

#pragma unroll
    for (int i = 0; i < 4; ++i) {
        int nt = wave * 4 + i;
        int ecol = nt * 16 + m16;
        const unsigned short* wrow = Wob + (size_t)ecol * E_;
        floatx4 acc = {0.f, 0.f, 0.f, 0.f};
#pragma unroll
        for (int kc = 0; kc < 8; ++kc) {
            bf16x8 bf = *(const bf16x8*)(wrow + kc * 32 + quad * 8);
            acc = __builtin_amdgcn_mfma_f32_16x16x32_bf16(af[kc], bf, acc, 0, 0, 0);
        }
        float bias = bo[ecol];
        size_t base = (size_t)(mbase + quad * 4) * E_ + ecol;
#pragma unroll
        for (int r = 0; r < 4; ++r)
            out[base + (size_t)r * E_] = acc[r] + bias;
    }
}

extern "C" void kernel_launch(void* const* d_in, const int* in_sizes, int n_in,
                              void* d_out, int out_size, void* d_ws, size_t ws_size,
                              hipStream_t stream) {
    const float* hs   = (const float*)d_in[0];
    const float* oq   = (const float*)d_in[1];
    const float* mask = (const float*)d_in[2];
    const float* Wq   = (const float*)d_in[3];
    const float* bq   = (const float*)d_in[4];
    const float* Wk   = (const float*)d_in[5];
    const float* bk   = (const float*)d_in[6];
    const float* Wv   = (const float*)d_in[7];
    const float* bv   = (const float*)d_in[8];
    const float* Wo   = (const float*)d_in[9];
    const float* bo   = (const float*)d_in[10];
    float* out = (float*)d_out;

    const size_t nBHTD = (size_t)B_ * H_ * T_ * DH_;   // 4,194,304 elems
    unsigned short* Qw    = (unsigned short*)d_ws;
    unsigned short* Kw    = Qw + nBHTD;
    unsigned short* Vtw   = Kw + nBHTD;
    unsigned short* attnw = Vtw + nBHTD;               // 4 x 8 MB
    unsigned short* Wpack = attnw + nBHTD;             // + 512 KB
    int* mask_nz = (int*)(Wpack + 4 * 65536);

    prepack_kernel<<<128, 256, 0, stream>>>(Wq, Wk, Wv, Wo, Wpack, mask_nz);
    qkvmask_kernel<<<1536 + 2048, 256, 0, stream>>>(
        hs, oq, Wpack, bq, bk, bv, Qw, Kw, Vtw, (const int*)mask, mask_nz);
    attn_kernel<<<B_ * H_ * (T_ / 128), 256, 0, stream>>>(Qw, Kw, Vtw, mask, mask_nz, attnw);
    oproj_kernel<<<(B_ * T_) / 16, 256, 0, stream>>>(attnw, Wpack + 3 * 65536, bo, out);
}

// Round 12
// 357.146 us; speedup vs baseline: 1.2438x; 1.0099x over previous
//
#include <hip/hip_runtime.h>

#define B_ 8
#define T_ 2048
#define E_ 256
#define H_ 8
#define DH_ 32
#define SCALING_ 0.17677669529663687f   // 1/sqrt(32)
#define LOG2E_ 1.4426950408889634f
// Q is pre-scaled by SCALING*log2(e): scores exit QK in log2 domain -> hw exp2
#define QSCALE_ (SCALING_ * LOG2E_)

typedef short bf16x8 __attribute__((ext_vector_type(8)));   // 8 bf16 in 4 VGPRs
typedef float floatx4 __attribute__((ext_vector_type(4)));

__device__ __forceinline__ unsigned short f2bf(float f) {
    union { float f; unsigned u; } v; v.f = f;
    unsigned r = v.u + 0x7FFFu + ((v.u >> 16) & 1u);   // RNE
    return (unsigned short)(r >> 16);
}

// pack 2 f32 -> 2 bf16 (round-half-up) in 3 VALU: add, add, v_perm_b32
__device__ __forceinline__ unsigned pk2(float a, float b) {
    union { float f; unsigned u; } ua, ub;
    ua.f = a; ub.f = b;
    return __builtin_amdgcn_perm(ub.u + 0x8000u, ua.u + 0x8000u, 0x07060302u);
}

__device__ __forceinline__ float fexp2(float x) {
#if __has_builtin(__builtin_amdgcn_exp2f)
    return __builtin_amdgcn_exp2f(x);
#else
    return exp2f(x);
#endif
}

__device__ __forceinline__ bf16x8 pack8(float4 a, float4 b) {
    bf16x8 o;
    o[0] = (short)f2bf(a.x); o[1] = (short)f2bf(a.y);
    o[2] = (short)f2bf(a.z); o[3] = (short)f2bf(a.w);
    o[4] = (short)f2bf(b.x); o[5] = (short)f2bf(b.y);
    o[6] = (short)f2bf(b.z); o[7] = (short)f2bf(b.w);
    return o;
}

// ---------------------------------------------------------------------------
// Kernel 0: weight prepack fp32 -> bf16 (tiny: 128 blocks).
// Also zeroes mask_nz (replaces the separate hipMemsetAsync dispatch).
// ---------------------------------------------------------------------------
__global__ __launch_bounds__(256) void prepack_kernel(
    const float* __restrict__ Wq, const float* __restrict__ Wk,
    const float* __restrict__ Wv, const float* __restrict__ Wo,
    unsigned short* __restrict__ Wpack, int* __restrict__ mask_nz) {
    if (blockIdx.x == 0 && threadIdx.x == 0) *mask_nz = 0;
    int idx = blockIdx.x * 256 + threadIdx.x;   // 32768 threads
    int m = idx >> 13;                           // matrix id 0..3
    int e = (idx & 8191) * 8;
    const float* W = (m == 0) ? Wq : (m == 1) ? Wk : (m == 2) ? Wv : Wo;
    float4 a = ((const float4*)(W + e))[0];
    float4 b = ((const float4*)(W + e))[1];
    *(bf16x8*)(Wpack + (size_t)m * 65536 + e) = pack8(a, b);
}

// ---------------------------------------------------------------------------
// Kernel 1: QKV projection (blocks 0..1535) FUSED with mask nonzero check
// (blocks 1536..3583) — the 128 MB mask scan overlaps the GEMM instead of
// serializing. mask_nz pre-zeroed by prepack_kernel; -0.0 -> slow path.
// (R12 final: nt-load dropped — R11 measured it null: FETCH unchanged.)
// ---------------------------------------------------------------------------
__global__ __launch_bounds__(256, 4) void qkvmask_kernel(
    const float* __restrict__ hs, const float* __restrict__ oq,
    const unsigned short* __restrict__ Wpack,
    const float* __restrict__ bq, const float* __restrict__ bk,
    const float* __restrict__ bv,
    unsigned short* __restrict__ Qw, unsigned short* __restrict__ Kw,
    unsigned short* __restrict__ Vtw,
    const int* __restrict__ mask, int* __restrict__ mask_nz) {
    if (blockIdx.x >= 1536) {
        // ---- mask scan: 2048 blocks, grid-stride int4 OR ----
        const size_t n4 = (size_t)B_ * T_ * T_ / 4;   // 8,388,608 int4
        size_t gid = (size_t)(blockIdx.x - 1536) * 256 + threadIdx.x;
        int acc = 0;
        for (size_t i = gid; i < n4; i += (size_t)2048 * 256) {
            int4 v = ((const int4*)mask)[i];
            acc |= v.x | v.y | v.z | v.w;
        }
        if (__builtin_amdgcn_ballot_w64(acc != 0)) {
            if ((threadIdx.x & 63) == 0) atomicOr(mask_nz, 1);
        }
        return;
    }
    __shared__ __align__(16) unsigned short sX[32][264];
    const int mat = blockIdx.x >> 9;          // 0=Q, 1=K, 2=V
    const int mbase = (blockIdx.x & 511) * 32;
    const int b = mbase >> 11, tbase = mbase & 2047;
    const int tid = threadIdx.x;

#pragma unroll
    for (int i = 0; i < 8; ++i) {
        int idx = tid + i * 256;
        int row = idx >> 6, c4 = idx & 63;
        float4 hv = ((const float4*)(hs + (size_t)(mbase + row) * E_))[c4];
        if (mat < 2) {
            float4 ov = ((const float4*)(oq + (size_t)(mbase + row) * E_))[c4];
            hv.x += ov.x; hv.y += ov.y; hv.z += ov.z; hv.w += ov.w;
        }
        ushort4 pb;
        pb.x = f2bf(hv.x); pb.y = f2bf(hv.y); pb.z = f2bf(hv.z); pb.w = f2bf(hv.w);
        *(ushort4*)&sX[row][c4 * 4] = pb;
    }
    __syncthreads();

    const int wave = tid >> 6, lane = tid & 63;
    const int quad = lane >> 4, m16 = lane & 15;
    const unsigned short* W = Wpack + (size_t)mat * 65536;

    bf16x8 xf[2][8];
#pragma unroll
    for (int hgrp = 0; hgrp < 2; ++hgrp)
#pragma unroll
        for (int kc = 0; kc < 8; ++kc)
            xf[hgrp][kc] = *(const bf16x8*)&sX[hgrp * 16 + m16][kc * 32 + quad * 8];

    if (mat < 2) {
        const float* bias = (mat == 0) ? bq : bk;
        unsigned short* Out = (mat == 0) ? Qw : Kw;
#pragma unroll
        for (int i = 0; i < 4; ++i) {
            int nt = wave * 4 + i;
            int ecol = nt * 16 + m16;
            const unsigned short* wrow = W + (size_t)ecol * E_;
            floatx4 acc0 = {0.f, 0.f, 0.f, 0.f};
            floatx4 acc1 = {0.f, 0.f, 0.f, 0.f};
#pragma unroll
            for (int kc = 0; kc < 8; ++kc) {
                bf16x8 bf = *(const bf16x8*)(wrow + kc * 32 + quad * 8);
                acc0 = __builtin_amdgcn_mfma_f32_16x16x32_bf16(xf[0][kc], bf, acc0, 0, 0, 0);
                acc1 = __builtin_amdgcn_mfma_f32_16x16x32_bf16(xf[1][kc], bf, acc1, 0, 0, 0);
            }
            float bs = bias[ecol];
            int h = ecol >> 5, dh = ecol & 31;
            size_t base0 = (((size_t)b * H_ + h) * T_ + (tbase + quad * 4)) * DH_ + dh;
            size_t base1 = base0 + (size_t)16 * DH_;
#pragma unroll
            for (int r = 0; r < 4; ++r) {
                float v0 = acc0[r] + bs, v1 = acc1[r] + bs;
                if (mat == 0) { v0 *= QSCALE_; v1 *= QSCALE_; }
                Out[base0 + (size_t)r * DH_] = f2bf(v0);
                Out[base1 + (size_t)r * DH_] = f2bf(v1);
            }
        }
    } else {
#pragma unroll
        for (int i = 0; i < 4; ++i) {
            int et = wave * 4 + i;
            int erow = et * 16 + m16;
            const unsigned short* wrow = W + (size_t)erow * E_;
            floatx4 acc0 = {0.f, 0.f, 0.f, 0.f};
            floatx4 acc1 = {0.f, 0.f, 0.f, 0.f};
#pragma unroll
            for (int kc = 0; kc < 8; ++kc) {
                bf16x8 wf = *(const bf16x8*)(wrow + kc * 32 + quad * 8);
                acc0 = __builtin_amdgcn_mfma_f32_16x16x32_bf16(wf, xf[0][kc], acc0, 0, 0, 0);
                acc1 = __builtin_amdgcn_mfma_f32_16x16x32_bf16(wf, xf[1][kc], acc1, 0, 0, 0);
            }
            int t0 = tbase + m16, t1 = t0 + 16;
#pragma unroll
            for (int r = 0; r < 4; ++r) {
                int ev = et * 16 + quad * 4 + r;
                int h = ev >> 5, dh = ev & 31;
                size_t vb = (((size_t)b * H_ + h) * DH_ + dh) * T_;
                Vtw[vb + t0] = f2bf(acc0[r] + bv[ev]);
                Vtw[vb + t1] = f2bf(acc1[r] + bv[ev]);
            }
        }
    }
}

// ---------------------------------------------------------------------------
// Kernel 2: flash attention — EXACT R7 (verified best: 99.7 µs attn, 356 µs
// total, VGPR 104, no spill). Dual q-stream, 4-wave blocks, (256,2) so the
// VGPR half of the unified budget is 128 (cap/2 law, verified R7), V
// prefetched one kt ahead in registers.
// Session ledger (what NOT to retry): occupancy packaging (R1-R4: HW grants
// 2 waves/SIMD at this footprint regardless), cross-phase PV lag (R5/R8:
// always spills at any cap), setprio (R9: null), qkvmask epilogue swap
// (R9: negative), nt mask loads (R11: null). Bank-conflict counter 2^23 is
// benign <=2-way aliasing (constant across 3 different LDS layouts).
// ---------------------------------------------------------------------------
__global__ __launch_bounds__(256, 2) void attn_kernel(
    const unsigned short* __restrict__ Qw, const unsigned short* __restrict__ Kw,
    const unsigned short* __restrict__ Vtw, const float* __restrict__ mask,
    const int* __restrict__ mask_nz, unsigned short* __restrict__ attnw) {
    __shared__ __align__(16) unsigned short sPT[4][2][16][136];  // [wave][stream][q][key^swz]
    const int tid = threadIdx.x;
    const int wave = tid >> 6, lane = tid & 63;
    const int quad = lane >> 4, m16 = lane & 15;
    const int swz = (m16 & 8) * 4;            // 0 or 32 shorts (64 B granule)
    const int bh = blockIdx.x & 63, qt = blockIdx.x >> 6;   // bh%8==h -> XCD
    const int b = bh >> 3, h = bh & 7;
    const int qA = qt * 128 + wave * 32;
    const int qB = qA + 16;
    const int mnz = *mask_nz;

    bf16x8 qfragA = *(const bf16x8*)(Qw + ((size_t)bh * T_ + qA + m16) * DH_ + quad * 8);
    bf16x8 qfragB = *(const bf16x8*)(Qw + ((size_t)bh * T_ + qB + m16) * DH_ + quad * 8);
    const unsigned short* Kb = Kw + (size_t)bh * T_ * DH_;
    const unsigned short* Vb = Vtw + (size_t)bh * DH_ * T_;
    const float* MbA = mask + ((size_t)b * T_ + qA + m16) * T_ + quad * 4;
    const float* MbB = MbA + (size_t)16 * T_;

    floatx4 O0A = {0.f, 0.f, 0.f, 0.f}, O1A = {0.f, 0.f, 0.f, 0.f};
    floatx4 O0B = {0.f, 0.f, 0.f, 0.f}, O1B = {0.f, 0.f, 0.f, 0.f};
    floatx4 LA  = {0.f, 0.f, 0.f, 0.f}, LB  = {0.f, 0.f, 0.f, 0.f};  // l accumulators
    float mprevA = -1e30f, mprevB = -1e30f;
    const floatx4 zero = {0.f, 0.f, 0.f, 0.f};

    bf16x8 ones8;
#pragma unroll
    for (int i = 0; i < 8; ++i) ones8[i] = (short)0x3F80;   // bf16 1.0

    bf16x8 kf[8];
#pragma unroll
    for (int c = 0; c < 8; ++c)
        kf[c] = *(const bf16x8*)(Kb + (size_t)(c * 16 + m16) * DH_ + quad * 8);

    // V prefetch for kt=0: rows m16 and 16+m16, keys 0..127.
    bf16x8 vf0[4], vf1[4];
#pragma unroll
    for (int sb = 0; sb < 4; ++sb) {
        vf0[sb] = *(const bf16x8*)(Vb + (size_t)m16 * T_ + sb * 32 + quad * 8);
        vf1[sb] = *(const bf16x8*)(Vb + (size_t)(16 + m16) * T_ + sb * 32 + quad * 8);
    }

    for (int kt = 0; kt < 16; ++kt) {
        const int s0 = kt * 128;
#pragma unroll
        for (int hf = 0; hf < 2; ++hf) {
            const int cb = hf * 4;
            floatx4 scA[4], scB[4];
#pragma unroll
            for (int c = 0; c < 4; ++c) {
                scA[c] = __builtin_amdgcn_mfma_f32_16x16x32_bf16(kf[cb + c], qfragA, zero, 0, 0, 0);
                scB[c] = __builtin_amdgcn_mfma_f32_16x16x32_bf16(kf[cb + c], qfragB, zero, 0, 0, 0);
            }
            if (kt < 15) {
#pragma unroll
                for (int c = 0; c < 4; ++c)
                    kf[cb + c] = *(const bf16x8*)(
                        Kb + (size_t)(s0 + 128 + (cb + c) * 16 + m16) * DH_ + quad * 8);
            }
            if (!mnz) {
                // FAST PATH: raw exp2, pack, LDS. No stats, no adds.
#pragma unroll
                for (int c = 0; c < 4; ++c) {
                    float a0 = fexp2(scA[c][0]), a1 = fexp2(scA[c][1]);
                    float a2 = fexp2(scA[c][2]), a3 = fexp2(scA[c][3]);
                    float b0 = fexp2(scB[c][0]), b1 = fexp2(scB[c][1]);
                    float b2 = fexp2(scB[c][2]), b3 = fexp2(scB[c][3]);
                    uint2 wa = {pk2(a0, a1), pk2(a2, a3)};
                    uint2 wb = {pk2(b0, b1), pk2(b2, b3)};
                    int col = (((cb + c) * 16) ^ swz) + quad * 4;
                    *(uint2*)&sPT[wave][0][m16][col] = wa;
                    *(uint2*)&sPT[wave][1][m16][col] = wb;
                }
            } else {
                // SLOW PATH: online softmax in log2 domain; mask scaled by log2e.
#pragma unroll
                for (int c = 0; c < 4; ++c) {
                    float4 ma = *(const float4*)(MbA + s0 + (cb + c) * 16);
                    float4 mb = *(const float4*)(MbB + s0 + (cb + c) * 16);
                    scA[c][0] += ma.x * LOG2E_; scA[c][1] += ma.y * LOG2E_;
                    scA[c][2] += ma.z * LOG2E_; scA[c][3] += ma.w * LOG2E_;
                    scB[c][0] += mb.x * LOG2E_; scB[c][1] += mb.y * LOG2E_;
                    scB[c][2] += mb.z * LOG2E_; scB[c][3] += mb.w * LOG2E_;
                }
                float mlA = -1e30f, mlB = -1e30f;
#pragma unroll
                for (int c = 0; c < 4; ++c) {
                    mlA = fmaxf(fmaxf(fmaxf(scA[c][0], scA[c][1]), fmaxf(scA[c][2], scA[c][3])), mlA);
                    mlB = fmaxf(fmaxf(fmaxf(scB[c][0], scB[c][1]), fmaxf(scB[c][2], scB[c][3])), mlB);
                }
                mlA = fmaxf(mlA, __shfl_xor(mlA, 16, 64));
                mlA = fmaxf(mlA, __shfl_xor(mlA, 32, 64));
                mlB = fmaxf(mlB, __shfl_xor(mlB, 16, 64));
                mlB = fmaxf(mlB, __shfl_xor(mlB, 32, 64));
                float mnA = fmaxf(mprevA, mlA), mnB = fmaxf(mprevB, mlB);
                float alA = fexp2(mprevA - mnA), alB = fexp2(mprevB - mnB);
                mprevA = mnA; mprevB = mnB;
#pragma unroll
                for (int r = 0; r < 4; ++r) {
                    O0A[r] *= alA; O1A[r] *= alA; LA[r] *= alA;
                    O0B[r] *= alB; O1B[r] *= alB; LB[r] *= alB;
                }
#pragma unroll
                for (int c = 0; c < 4; ++c) {
                    float a0 = fexp2(scA[c][0] - mnA), a1 = fexp2(scA[c][1] - mnA);
                    float a2 = fexp2(scA[c][2] - mnA), a3 = fexp2(scA[c][3] - mnA);
                    float b0 = fexp2(scB[c][0] - mnB), b1 = fexp2(scB[c][1] - mnB);
                    float b2 = fexp2(scB[c][2] - mnB), b3 = fexp2(scB[c][3] - mnB);
                    uint2 wa = {pk2(a0, a1), pk2(a2, a3)};
                    uint2 wb = {pk2(b0, b1), pk2(b2, b3)};
                    int col = (((cb + c) * 16) ^ swz) + quad * 4;
                    *(uint2*)&sPT[wave][0][m16][col] = wa;
                    *(uint2*)&sPT[wave][1][m16][col] = wb;
                }
            }
        }
        // PV + l: O^T += V^T·P, L += 1^T·P (MFMA pipe), V in prefetched regs.
#pragma unroll
        for (int sb = 0; sb < 4; ++sb) {
            int col = ((sb * 32) ^ swz) + quad * 8;
            bf16x8 pbA = *(const bf16x8*)&sPT[wave][0][m16][col];
            bf16x8 pbB = *(const bf16x8*)&sPT[wave][1][m16][col];
            O0A = __builtin_amdgcn_mfma_f32_16x16x32_bf16(vf0[sb], pbA, O0A, 0, 0, 0);
            O0B = __builtin_amdgcn_mfma_f32_16x16x32_bf16(vf0[sb], pbB, O0B, 0, 0, 0);
            O1A = __builtin_amdgcn_mfma_f32_16x16x32_bf16(vf1[sb], pbA, O1A, 0, 0, 0);
            O1B = __builtin_amdgcn_mfma_f32_16x16x32_bf16(vf1[sb], pbB, O1B, 0, 0, 0);
            LA  = __builtin_amdgcn_mfma_f32_16x16x32_bf16(ones8, pbA, LA, 0, 0, 0);
            LB  = __builtin_amdgcn_mfma_f32_16x16x32_bf16(ones8, pbB, LB, 0, 0, 0);
        }
        // V prefetch for kt+1 — a full QK+exp2 phase of latency cover.
        if (kt < 15) {
#pragma unroll
            for (int sb = 0; sb < 4; ++sb) {
                vf0[sb] = *(const bf16x8*)(Vb + (size_t)m16 * T_ + s0 + 128 + sb * 32 + quad * 8);
                vf1[sb] = *(const bf16x8*)(Vb + (size_t)(16 + m16) * T_ + s0 + 128 + sb * 32 + quad * 8);
            }
        }
    }
    // LA/LB rows all hold l[q=m16] — no shuffles needed.
    float invA = 1.0f / LA[0], invB = 1.0f / LB[0];
    size_t obA = ((size_t)b * T_ + qA + m16) * E_ + h * DH_ + quad * 4;
    size_t obB = ((size_t)b * T_ + qB + m16) * E_ + h * DH_ + quad * 4;
    ushort4 sv;
    sv.x = f2bf(O0A[0] * invA); sv.y = f2bf(O0A[1] * invA);
    sv.z = f2bf(O0A[2] * invA); sv.w = f2bf(O0A[3] * invA);
    *(ushort4*)(attnw + obA) = sv;
    sv.x = f2bf(O1A[0] * invA); sv.y = f2bf(O1A[1] * invA);
    sv.z = f2bf(O1A[2] * invA); sv.w = f2bf(O1A[3] * invA);
    *(ushort4*)(attnw + obA + 16) = sv;
    sv.x = f2bf(O0B[0] * invB); sv.y = f2bf(O0B[1] * invB);
    sv.z = f2bf(O0B[2] * invB); sv.w = f2bf(O0B[3] * invB);
    *(ushort4*)(attnw + obB) = sv;
    sv.x = f2bf(O1B[0] * invB); sv.y = f2bf(O1B[1] * invB);
    sv.z = f2bf(O1B[2] * invB); sv.w = f2bf(O1B[3] * invB);
    *(ushort4*)(attnw + obB + 16) = sv;
}

// ---------------------------------------------------------------------------
// Kernel 3: output projection: out = attn @ Wo^T + bo  (fp32 out, bf16 weights)
// ---------------------------------------------------------------------------
__global__ __launch_bounds__(256, 4) void oproj_kernel(
    const unsigned short* __restrict__ attnw, const unsigned short* __restrict__ Wob,
    const float* __restrict__ bo, float* __restrict__ out) {
    __shared__ __align__(16) unsigned short sA[16][264];
    const int tid = threadIdx.x;
    const int mbase = blockIdx.x * 16;
#pragma unroll
    for (int i = 0; i < 4; ++i) {
        int idx = tid + i * 256;
        int row = idx >> 6, c4 = idx & 63;
        const ushort4 a = ((const ushort4*)(attnw + (size_t)(mbase + row) * E_))[c4];
        *(ushort4*)&sA[row][c4 * 4] = a;
    }
    __syncthreads();
    const int wave = tid >> 6, lane = tid & 63;
    const int quad = lane >> 4, m16 = lane & 15;

    bf16x8 af[8];
#pragma unroll
    for (int kc = 0; kc < 8; ++kc)
        af[kc] = *(const bf16x8*)&sA[m16][kc * 32 + quad * 8];

#pragma unroll
    for (int i = 0; i < 4; ++i) {
        int nt = wave * 4 + i;
        int ecol = nt * 16 + m16;
        const unsigned short* wrow = Wob + (size_t)ecol * E_;
        floatx4 acc = {0.f, 0.f, 0.f, 0.f};
#pragma unroll
        for (int kc = 0; kc < 8; ++kc) {
            bf16x8 bf = *(const bf16x8*)(wrow + kc * 32 + quad * 8);
            acc = __builtin_amdgcn_mfma_f32_16x16x32_bf16(af[kc], bf, acc, 0, 0, 0);
        }
        float bias = bo[ecol];
        size_t base = (size_t)(mbase + quad * 4) * E_ + ecol;
#pragma unroll
        for (int r = 0; r < 4; ++r)
            out[base + (size_t)r * E_] = acc[r] + bias;
    }
}

extern "C" void kernel_launch(void* const* d_in, const int* in_sizes, int n_in,
                              void* d_out, int out_size, void* d_ws, size_t ws_size,
                              hipStream_t stream) {
    const float* hs   = (const float*)d_in[0];
    const float* oq   = (const float*)d_in[1];
    const float* mask = (const float*)d_in[2];
    const float* Wq   = (const float*)d_in[3];
    const float* bq   = (const float*)d_in[4];
    const float* Wk   = (const float*)d_in[5];
    const float* bk   = (const float*)d_in[6];
    const float* Wv   = (const float*)d_in[7];
    const float* bv   = (const float*)d_in[8];
    const float* Wo   = (const float*)d_in[9];
    const float* bo   = (const float*)d_in[10];
    float* out = (float*)d_out;

    const size_t nBHTD = (size_t)B_ * H_ * T_ * DH_;   // 4,194,304 elems
    unsigned short* Qw    = (unsigned short*)d_ws;
    unsigned short* Kw    = Qw + nBHTD;
    unsigned short* Vtw   = Kw + nBHTD;
    unsigned short* attnw = Vtw + nBHTD;               // 4 x 8 MB
    unsigned short* Wpack = attnw + nBHTD;             // + 512 KB
    int* mask_nz = (int*)(Wpack + 4 * 65536);

    prepack_kernel<<<128, 256, 0, stream>>>(Wq, Wk, Wv, Wo, Wpack, mask_nz);
    qkvmask_kernel<<<1536 + 2048, 256, 0, stream>>>(
        hs, oq, Wpack, bq, bk, bv, Qw, Kw, Vtw, (const int*)mask, mask_nz);
    attn_kernel<<<B_ * H_ * (T_ / 128), 256, 0, stream>>>(Qw, Kw, Vtw, mask, mask_nz, attnw);
    oproj_kernel<<<(B_ * T_) / 16, 256, 0, stream>>>(attnw, Wpack + 3 * 65536, bo, out);
}